// Round 1
// baseline (837.807 us; speedup 1.0000x reference)
//
#include <hip/hip_runtime.h>
#include <math.h>

#define N_NODES 10000
#define N_EDGES 160000
#define N_GRAPHS 64

// ---------------------------------------------------------------------------
// Fused GEMM: C[M,W] = A[M,K] @ B[K,W] + bias[W]
// 64x64 block tile, 256 threads, 4x4 per thread, K (<=128) fully staged.
// ---------------------------------------------------------------------------
template <int K>
__global__ __launch_bounds__(256) void gemm_bias(
    const float* __restrict__ A, const float* __restrict__ B,
    const float* __restrict__ bias, float* __restrict__ C, int M, int W) {
  __shared__ float Ast[K][68];  // [k][m] (A transposed in LDS)
  __shared__ float Bs[K][68];   // [k][n]
  const int tid = threadIdx.x;
  const int tx = tid & 15, ty = tid >> 4;
  const int row0 = blockIdx.y * 64, col0 = blockIdx.x * 64;

  for (int i = tid; i < 64 * K; i += 256) {
    int r = i / K, c = i % K;  // consecutive i -> consecutive c: coalesced A read
    int gr = row0 + r;
    Ast[c][r] = (gr < M) ? A[(size_t)gr * K + c] : 0.f;
  }
  for (int i = tid; i < 64 * K; i += 256) {
    int r = i >> 6, c = i & 63;  // coalesced B read (W multiple of 64)
    Bs[r][c] = B[(size_t)r * W + col0 + c];
  }
  __syncthreads();

  float acc[4][4] = {};
#pragma unroll 4
  for (int k = 0; k < K; ++k) {
    float4 a4 = *reinterpret_cast<const float4*>(&Ast[k][ty * 4]);
    float4 b4 = *reinterpret_cast<const float4*>(&Bs[k][tx * 4]);
    float a[4] = {a4.x, a4.y, a4.z, a4.w};
    float b[4] = {b4.x, b4.y, b4.z, b4.w};
#pragma unroll
    for (int m_ = 0; m_ < 4; ++m_)
#pragma unroll
      for (int n_ = 0; n_ < 4; ++n_) acc[m_][n_] += a[m_] * b[n_];
  }

  float bb[4];
#pragma unroll
  for (int n_ = 0; n_ < 4; ++n_) bb[n_] = bias[col0 + tx * 4 + n_];
#pragma unroll
  for (int m_ = 0; m_ < 4; ++m_) {
    int gr = row0 + ty * 4 + m_;
    if (gr < M) {
      float4 o;
      o.x = acc[m_][0] + bb[0];
      o.y = acc[m_][1] + bb[1];
      o.z = acc[m_][2] + bb[2];
      o.w = acc[m_][3] + bb[3];
      *reinterpret_cast<float4*>(C + (size_t)gr * W + col0 + tx * 4) = o;
    }
  }
}

// ---------------------------------------------------------------------------
// Weight/bias concat pack: Wcat[K][3*HD+DOUT] = [wq|wk|wv|ws], bcat likewise.
// ---------------------------------------------------------------------------
__global__ void pack_w(const float* __restrict__ wq, const float* __restrict__ wk,
                       const float* __restrict__ wv, const float* __restrict__ wsk,
                       const float* __restrict__ bq, const float* __restrict__ bk,
                       const float* __restrict__ bv, const float* __restrict__ bs,
                       float* __restrict__ Wcat, float* __restrict__ bcat,
                       int K, int HD, int DOUT) {
  const int W = 3 * HD + DOUT;
  const int total = (K + 1) * W;
  for (int i = blockIdx.x * blockDim.x + threadIdx.x; i < total;
       i += gridDim.x * blockDim.x) {
    int k = i / W, j = i % W;
    float v;
    if (j < HD)           v = (k < K) ? wq[k * HD + j]             : bq[j];
    else if (j < 2 * HD)  v = (k < K) ? wk[k * HD + (j - HD)]      : bk[j - HD];
    else if (j < 3 * HD)  v = (k < K) ? wv[k * HD + (j - 2 * HD)]  : bv[j - 2 * HD];
    else                  v = (k < K) ? wsk[k * DOUT + (j - 3 * HD)] : bs[j - 3 * HD];
    if (k < K) Wcat[i] = v; else bcat[j] = v;
  }
}

// ---------------------------------------------------------------------------
// CSR build over dst
// ---------------------------------------------------------------------------
__global__ void zero_ints(int* __restrict__ a, int n) {
  for (int i = blockIdx.x * blockDim.x + threadIdx.x; i < n;
       i += gridDim.x * blockDim.x) a[i] = 0;
}

__global__ void count_dst(const int* __restrict__ dst, int* __restrict__ cnt) {
  int e = blockIdx.x * blockDim.x + threadIdx.x;
  if (e < N_EDGES) atomicAdd(&cnt[dst[e]], 1);
}

__global__ __launch_bounds__(256) void scan_offs(const int* __restrict__ cnt,
                                                 int* __restrict__ offs) {
  __shared__ int part[256];
  const int t = threadIdx.x;
  const int chunk = (N_NODES + 255) / 256;
  const int b = t * chunk;
  const int e = min(N_NODES, b + chunk);
  int s = 0;
  for (int i = b; i < e; ++i) s += cnt[i];
  part[t] = s;
  __syncthreads();
  for (int off = 1; off < 256; off <<= 1) {
    int v = (t >= off) ? part[t - off] : 0;
    __syncthreads();
    part[t] += v;
    __syncthreads();
  }
  int pre = (t == 0) ? 0 : part[t - 1];
  for (int i = b; i < e; ++i) { offs[i] = pre; pre += cnt[i]; }
  if (t == 0) offs[N_NODES] = part[255];
}

__global__ void scatter_edges(const int* __restrict__ dst, const int* __restrict__ offs,
                              int* __restrict__ cursor, int* __restrict__ elist) {
  int e = blockIdx.x * blockDim.x + threadIdx.x;
  if (e < N_EDGES) {
    int d = dst[e];
    int pos = offs[d] + atomicAdd(&cursor[d], 1);
    elist[pos] = e;
  }
}

// ---------------------------------------------------------------------------
// Fused edge kernel: per dst node, online-softmax attention over incoming
// edges with edge-conditioned keys (e = edge_attr @ we computed on the fly),
// head-mean + skip + ELU. One wave per node, 4 nodes per block.
// QKVS layout per node: [Q(HD) | K(HD) | V(HD) | S(DOUT)], stride 3*HD+DOUT.
// ---------------------------------------------------------------------------
template <int DOUT>
__global__ __launch_bounds__(256) void edge_attn(
    const float* __restrict__ QKVS, const float* __restrict__ edge_attr,
    const float* __restrict__ we, const int* __restrict__ src,
    const int* __restrict__ offs, const int* __restrict__ elist,
    float* __restrict__ out) {
  constexpr int HD = 4 * DOUT;
  constexpr int R = HD / 64;
  constexpr int STRIDE = 3 * HD + DOUT;
  const float SCALE = (DOUT == 64) ? 0.125f : 0.08838834764831845f;

  __shared__ float we_s[16 * HD];
  for (int i = threadIdx.x; i < 16 * HD; i += 256) we_s[i] = we[i];
  __syncthreads();

  const int lane = threadIdx.x & 63;
  const int n = blockIdx.x * 4 + (threadIdx.x >> 6);  // N_NODES % 4 == 0

  const float* base = QKVS + (size_t)n * STRIDE;
  float q[R], acc[R];
#pragma unroll
  for (int r = 0; r < R; ++r) {
    q[r] = base[(r << 6) + lane];
    acc[r] = 0.f;
  }
  float m[4] = {-1e30f, -1e30f, -1e30f, -1e30f};
  float l[4] = {0.f, 0.f, 0.f, 0.f};

  const int s0 = offs[n], s1 = offs[n + 1];
  for (int ii = s0; ii < s1; ++ii) {
    const int e = elist[ii];
    const int s = src[e];
    float eav = (lane < 16) ? edge_attr[(size_t)e * 16 + lane] : 0.f;
    const float* kb = QKVS + (size_t)s * STRIDE + HD;

    float ev[R];
#pragma unroll
    for (int r = 0; r < R; ++r) ev[r] = 0.f;
#pragma unroll
    for (int d = 0; d < 16; ++d) {
      float a = __shfl(eav, d);
#pragma unroll
      for (int r = 0; r < R; ++r) ev[r] += a * we_s[d * HD + (r << 6) + lane];
    }

    float part[R];
#pragma unroll
    for (int r = 0; r < R; ++r) part[r] = q[r] * (kb[(r << 6) + lane] + ev[r]);
#pragma unroll
    for (int off = 32; off > 0; off >>= 1) {
#pragma unroll
      for (int r = 0; r < R; ++r) part[r] += __shfl_xor(part[r], off);
    }

    float fac[4], p[4];
#pragma unroll
    for (int h = 0; h < 4; ++h) {
      float a = ((DOUT == 64) ? part[h] : (part[2 * h] + part[2 * h + 1])) * SCALE;
      float mn = fmaxf(m[h], a);
      fac[h] = __expf(m[h] - mn);
      p[h] = __expf(a - mn);
      l[h] = l[h] * fac[h] + p[h];
      m[h] = mn;
    }

    const float* vb = kb + HD;
#pragma unroll
    for (int r = 0; r < R; ++r) {
      int h = (DOUT == 64) ? r : (r >> 1);
      acc[r] = acc[r] * fac[h] + p[h] * (vb[(r << 6) + lane] + ev[r]);
    }
  }

  float inv[4];
#pragma unroll
  for (int h = 0; h < 4; ++h) inv[h] = (l[h] > 0.f) ? 1.f / l[h] : 0.f;
#pragma unroll
  for (int r = 0; r < R; ++r) acc[r] *= inv[(DOUT == 64) ? r : (r >> 1)];

  const float* sb = base + 3 * HD;
  if (DOUT == 64) {
    float o = 0.25f * (acc[0] + acc[1] + acc[2] + acc[3]) + sb[lane];
    out[(size_t)n * 64 + lane] = (o > 0.f) ? o : expm1f(o);
  } else {
    float o0 = 0.25f * (acc[0] + acc[2] + acc[4] + acc[6]) + sb[lane];
    float o1 = 0.25f * (acc[1] + acc[3] + acc[5] + acc[7]) + sb[64 + lane];
    out[(size_t)n * 128 + lane] = (o0 > 0.f) ? o0 : expm1f(o0);
    out[(size_t)n * 128 + 64 + lane] = (o1 > 0.f) ? o1 : expm1f(o1);
  }
}

// ---------------------------------------------------------------------------
// Global mean pool over graphs
// ---------------------------------------------------------------------------
__global__ void pool_zero(float* __restrict__ out, int* __restrict__ gcnt) {
  int i = blockIdx.x * blockDim.x + threadIdx.x;
  if (i < N_GRAPHS * 64) out[i] = 0.f;
  if (i < N_GRAPHS) gcnt[i] = 0;
}

__global__ void pool_acc(const float* __restrict__ h, const int* __restrict__ batch,
                         float* __restrict__ out, int* __restrict__ gcnt) {
  int i = blockIdx.x * blockDim.x + threadIdx.x;
  if (i >= N_NODES * 64) return;
  int n = i >> 6, c = i & 63;
  int g = batch[n];
  atomicAdd(&out[g * 64 + c], h[(size_t)n * 64 + c]);
  if (c == 0) atomicAdd(&gcnt[g], 1);
}

__global__ void pool_div(float* __restrict__ out, const int* __restrict__ gcnt) {
  int i = blockIdx.x * blockDim.x + threadIdx.x;
  if (i < N_GRAPHS * 64) out[i] /= (float)max(gcnt[i >> 6], 1);
}

// ---------------------------------------------------------------------------
extern "C" void kernel_launch(void* const* d_in, const int* in_sizes, int n_in,
                              void* d_out, int out_size, void* d_ws, size_t ws_size,
                              hipStream_t stream) {
  const float* x = (const float*)d_in[0];
  const int* edge_index = (const int*)d_in[1];
  const float* edge_attr = (const float*)d_in[2];
  const int* batch = (const int*)d_in[3];
  const int* srcp = edge_index;            // edge_index[0]
  const int* dstp = edge_index + N_EDGES;  // edge_index[1]

  // Input ordering: dict order (wq,wk,wv,we,ws,bq,bk,bv,bs) vs arg order
  // (wq,bq,wk,bk,wv,bv,we,ws,bs). Distinguish via in_sizes[5].
  const bool dict_order = in_sizes[5] > 1024;
  const float *wq[3], *wk[3], *wv[3], *wep[3], *wsk[3], *bq[3], *bk[3], *bv[3], *bs[3];
  for (int L = 0; L < 3; ++L) {
    int b = 4 + L * 9;
    if (dict_order) {
      wq[L] = (const float*)d_in[b + 0];
      wk[L] = (const float*)d_in[b + 1];
      wv[L] = (const float*)d_in[b + 2];
      wep[L] = (const float*)d_in[b + 3];
      wsk[L] = (const float*)d_in[b + 4];
      bq[L] = (const float*)d_in[b + 5];
      bk[L] = (const float*)d_in[b + 6];
      bv[L] = (const float*)d_in[b + 7];
      bs[L] = (const float*)d_in[b + 8];
    } else {
      wq[L] = (const float*)d_in[b + 0];
      bq[L] = (const float*)d_in[b + 1];
      wk[L] = (const float*)d_in[b + 2];
      bk[L] = (const float*)d_in[b + 3];
      wv[L] = (const float*)d_in[b + 4];
      bv[L] = (const float*)d_in[b + 5];
      wep[L] = (const float*)d_in[b + 6];
      wsk[L] = (const float*)d_in[b + 7];
      bs[L] = (const float*)d_in[b + 8];
    }
  }

  // Workspace carve (floats then ints).
  float* qkvs = (float*)d_ws;                    // N * 1664 max
  float* h1 = qkvs + (size_t)N_NODES * 1664;     // N * 128
  float* h2 = h1 + (size_t)N_NODES * 128;        // N * 128
  float* Wcat = h2 + (size_t)N_NODES * 128;      // 128 * 1664 max
  float* bcat = Wcat + 128 * 1664;               // 2048
  int* cnt = (int*)(bcat + 2048);                // N
  int* cursor = cnt + N_NODES;                   // N
  int* offs = cursor + N_NODES;                  // N + 1
  int* elist = offs + N_NODES + 1;               // E
  int* gcnt = elist + N_EDGES;                   // 64

  // ---- CSR build over dst (same for all layers) ----
  zero_ints<<<79, 256, 0, stream>>>(cnt, 2 * N_NODES);  // cnt + cursor
  count_dst<<<(N_EDGES + 255) / 256, 256, 0, stream>>>(dstp, cnt);
  scan_offs<<<1, 256, 0, stream>>>(cnt, offs);
  scatter_edges<<<(N_EDGES + 255) / 256, 256, 0, stream>>>(dstp, offs, cursor, elist);

  // ---- 3 TransformerConv layers ----
  const int Kdim[3] = {128, 64, 128};
  const int Dout[3] = {64, 128, 64};
  const float* hin = x;
  float* hout[3] = {h1, h2, h1};

  for (int L = 0; L < 3; ++L) {
    const int K = Kdim[L], DOUT = Dout[L], HD = 4 * DOUT, W = 3 * HD + DOUT;
    pack_w<<<((K + 1) * W + 255) / 256, 256, 0, stream>>>(
        wq[L], wk[L], wv[L], wsk[L], bq[L], bk[L], bv[L], bs[L], Wcat, bcat, K, HD, DOUT);
    dim3 ggrid(W / 64, (N_NODES + 63) / 64);
    if (K == 128)
      gemm_bias<128><<<ggrid, 256, 0, stream>>>(hin, Wcat, bcat, qkvs, N_NODES, W);
    else
      gemm_bias<64><<<ggrid, 256, 0, stream>>>(hin, Wcat, bcat, qkvs, N_NODES, W);
    if (DOUT == 64)
      edge_attn<64><<<N_NODES / 4, 256, 0, stream>>>(qkvs, edge_attr, wep[L], srcp,
                                                     offs, elist, hout[L]);
    else
      edge_attn<128><<<N_NODES / 4, 256, 0, stream>>>(qkvs, edge_attr, wep[L], srcp,
                                                      offs, elist, hout[L]);
    hin = hout[L];
  }

  // ---- global mean pool ----
  pool_zero<<<17, 256, 0, stream>>>((float*)d_out, gcnt);
  pool_acc<<<(N_NODES * 64 + 255) / 256, 256, 0, stream>>>(h1, batch, (float*)d_out, gcnt);
  pool_div<<<16, 256, 0, stream>>>((float*)d_out, gcnt);
}

// Round 2
// 640.679 us; speedup vs baseline: 1.3077x; 1.3077x over previous
//
#include <hip/hip_runtime.h>
#include <math.h>

#define N_NODES 10000
#define N_EDGES 160000
#define N_GRAPHS 64

// ---------------------------------------------------------------------------
// Fused GEMM: C[M,W] = A[M,K] @ B[K,W] + bias[W]
// 64x64 block tile, 256 threads, 4x4 per thread, K (<=128) fully staged.
// ---------------------------------------------------------------------------
template <int K>
__global__ __launch_bounds__(256) void gemm_bias(
    const float* __restrict__ A, const float* __restrict__ B,
    const float* __restrict__ bias, float* __restrict__ C, int M, int W) {
  __shared__ float Ast[K][68];  // [k][m] (A transposed in LDS)
  __shared__ float Bs[K][68];   // [k][n]
  const int tid = threadIdx.x;
  const int tx = tid & 15, ty = tid >> 4;
  const int row0 = blockIdx.y * 64, col0 = blockIdx.x * 64;

  for (int i = tid; i < 64 * K; i += 256) {
    int r = i / K, c = i % K;  // consecutive i -> consecutive c: coalesced A read
    int gr = row0 + r;
    Ast[c][r] = (gr < M) ? A[(size_t)gr * K + c] : 0.f;
  }
  for (int i = tid; i < 64 * K; i += 256) {
    int r = i >> 6, c = i & 63;  // coalesced B read (W multiple of 64)
    Bs[r][c] = B[(size_t)r * W + col0 + c];
  }
  __syncthreads();

  float acc[4][4] = {};
#pragma unroll 4
  for (int k = 0; k < K; ++k) {
    float4 a4 = *reinterpret_cast<const float4*>(&Ast[k][ty * 4]);
    float4 b4 = *reinterpret_cast<const float4*>(&Bs[k][tx * 4]);
    float a[4] = {a4.x, a4.y, a4.z, a4.w};
    float b[4] = {b4.x, b4.y, b4.z, b4.w};
#pragma unroll
    for (int m_ = 0; m_ < 4; ++m_)
#pragma unroll
      for (int n_ = 0; n_ < 4; ++n_) acc[m_][n_] += a[m_] * b[n_];
  }

  float bb[4];
#pragma unroll
  for (int n_ = 0; n_ < 4; ++n_) bb[n_] = bias[col0 + tx * 4 + n_];
#pragma unroll
  for (int m_ = 0; m_ < 4; ++m_) {
    int gr = row0 + ty * 4 + m_;
    if (gr < M) {
      float4 o;
      o.x = acc[m_][0] + bb[0];
      o.y = acc[m_][1] + bb[1];
      o.z = acc[m_][2] + bb[2];
      o.w = acc[m_][3] + bb[3];
      *reinterpret_cast<float4*>(C + (size_t)gr * W + col0 + tx * 4) = o;
    }
  }
}

// ---------------------------------------------------------------------------
// Weight/bias concat pack: Wcat[K][3*HD+DOUT] = [wq|wk|wv|ws], bcat likewise.
// ---------------------------------------------------------------------------
__global__ void pack_w(const float* __restrict__ wq, const float* __restrict__ wk,
                       const float* __restrict__ wv, const float* __restrict__ wsk,
                       const float* __restrict__ bq, const float* __restrict__ bk,
                       const float* __restrict__ bv, const float* __restrict__ bs,
                       float* __restrict__ Wcat, float* __restrict__ bcat,
                       int K, int HD, int DOUT) {
  const int W = 3 * HD + DOUT;
  const int total = (K + 1) * W;
  for (int i = blockIdx.x * blockDim.x + threadIdx.x; i < total;
       i += gridDim.x * blockDim.x) {
    int k = i / W, j = i % W;
    float v;
    if (j < HD)           v = (k < K) ? wq[k * HD + j]             : bq[j];
    else if (j < 2 * HD)  v = (k < K) ? wk[k * HD + (j - HD)]      : bk[j - HD];
    else if (j < 3 * HD)  v = (k < K) ? wv[k * HD + (j - 2 * HD)]  : bv[j - 2 * HD];
    else                  v = (k < K) ? wsk[k * DOUT + (j - 3 * HD)] : bs[j - 3 * HD];
    if (k < K) Wcat[i] = v; else bcat[j] = v;
  }
}

// ---------------------------------------------------------------------------
// CSR build over dst (+ permute src and edge_attr into CSR order)
// ---------------------------------------------------------------------------
__global__ void zero_ints(int* __restrict__ a, int n) {
  for (int i = blockIdx.x * blockDim.x + threadIdx.x; i < n;
       i += gridDim.x * blockDim.x) a[i] = 0;
}

__global__ void count_dst(const int* __restrict__ dst, int* __restrict__ cnt) {
  int e = blockIdx.x * blockDim.x + threadIdx.x;
  if (e < N_EDGES) atomicAdd(&cnt[dst[e]], 1);
}

__global__ __launch_bounds__(256) void scan_offs(const int* __restrict__ cnt,
                                                 int* __restrict__ offs) {
  __shared__ int part[256];
  const int t = threadIdx.x;
  const int chunk = (N_NODES + 255) / 256;
  const int b = t * chunk;
  const int e = min(N_NODES, b + chunk);
  int s = 0;
  for (int i = b; i < e; ++i) s += cnt[i];
  part[t] = s;
  __syncthreads();
  for (int off = 1; off < 256; off <<= 1) {
    int v = (t >= off) ? part[t - off] : 0;
    __syncthreads();
    part[t] += v;
    __syncthreads();
  }
  int pre = (t == 0) ? 0 : part[t - 1];
  for (int i = b; i < e; ++i) { offs[i] = pre; pre += cnt[i]; }
  if (t == 0) offs[N_NODES] = part[255];
}

__global__ void scatter_csr(const int* __restrict__ src, const int* __restrict__ dst,
                            const float* __restrict__ edge_attr,
                            const int* __restrict__ offs, int* __restrict__ cursor,
                            int* __restrict__ csr_src, float* __restrict__ csr_ea) {
  int e = blockIdx.x * blockDim.x + threadIdx.x;
  if (e < N_EDGES) {
    int d = dst[e];
    int pos = offs[d] + atomicAdd(&cursor[d], 1);
    csr_src[pos] = src[e];
    float4* o4 = reinterpret_cast<float4*>(csr_ea + (size_t)pos * 16);
    const float4* s4 = reinterpret_cast<const float4*>(edge_attr + (size_t)e * 16);
    o4[0] = s4[0]; o4[1] = s4[1]; o4[2] = s4[2]; o4[3] = s4[3];
  }
}

// ---------------------------------------------------------------------------
// Per-node G precompute: G[n, h, d] = SCALE * sum_c q[n,h,c] * we[d, h*DOUT+c]
// One wave per node; lane l -> (h = l>>4, owns channels c0..c0+4*NV-1 for the
// partial sums; result kept by lane with (l&15)==d).
// ---------------------------------------------------------------------------
template <int DOUT>
__global__ __launch_bounds__(256) void g_precompute(
    const float* __restrict__ QKVS, const float* __restrict__ we,
    float* __restrict__ G) {
  constexpr int HD = 4 * DOUT;
  constexpr int STRIDE = 3 * HD + DOUT;
  constexpr int NV = DOUT / 64;  // float4s per lane
  const float SCALE = (DOUT == 64) ? 0.125f : 0.08838834764831845f;

  __shared__ float we_s[16 * HD];
  for (int i = threadIdx.x; i < 16 * HD; i += 256) we_s[i] = we[i];
  __syncthreads();

  const int lane = threadIdx.x & 63;
  const int h = lane >> 4, t16 = lane & 15;
  const int n = blockIdx.x * 4 + (threadIdx.x >> 6);
  const int c0 = t16 * 4 * NV;

  float4 q[NV];
  const float* qb = QKVS + (size_t)n * STRIDE + h * DOUT + c0;
#pragma unroll
  for (int v = 0; v < NV; ++v) q[v] = *reinterpret_cast<const float4*>(qb + 4 * v);

  float gval = 0.f;
#pragma unroll
  for (int d = 0; d < 16; ++d) {
    float p = 0.f;
    const float* wb = we_s + d * HD + h * DOUT + c0;
#pragma unroll
    for (int v = 0; v < NV; ++v) {
      float4 w4 = *reinterpret_cast<const float4*>(wb + 4 * v);
      p += q[v].x * w4.x + q[v].y * w4.y + q[v].z * w4.z + q[v].w * w4.w;
    }
    p += __shfl_xor(p, 1);
    p += __shfl_xor(p, 2);
    p += __shfl_xor(p, 4);
    p += __shfl_xor(p, 8);
    if (t16 == d) gval = p;
  }
  G[(size_t)n * 64 + lane] = gval * SCALE;
}

// ---------------------------------------------------------------------------
// Fused edge kernel, head-local lanes + folded edge-feature algebra.
// alpha[e,h] = SCALE*(q[dst,h]·k[src,h]) + ea[e]·G[dst,h]   (G pre-scaled)
// agg[h]    = sum attn·v[src,h]  +  (sum attn·ea) @ we[:,h,:]
// Lane l: head h=l>>4, channels c0 = (l&15)*4*NV .. +4*NV-1.
// ---------------------------------------------------------------------------
template <int DOUT>
__global__ __launch_bounds__(256) void edge_attn(
    const float* __restrict__ QKVS, const float* __restrict__ we,
    const float* __restrict__ G, const int* __restrict__ csr_src,
    const float* __restrict__ csr_ea, const int* __restrict__ offs,
    float* __restrict__ out) {
  constexpr int HD = 4 * DOUT;
  constexpr int STRIDE = 3 * HD + DOUT;
  constexpr int NV = DOUT / 64;
  const float SCALE = (DOUT == 64) ? 0.125f : 0.08838834764831845f;

  __shared__ float we_s[16 * HD];
  for (int i = threadIdx.x; i < 16 * HD; i += 256) we_s[i] = we[i];
  __syncthreads();

  const int lane = threadIdx.x & 63;
  const int h = lane >> 4, t16 = lane & 15;
  const int n = blockIdx.x * 4 + (threadIdx.x >> 6);
  const int c0 = t16 * 4 * NV;

  const float* base = QKVS + (size_t)n * STRIDE;
  float4 q[NV], acc[NV];
#pragma unroll
  for (int v = 0; v < NV; ++v) {
    float4 qq = *reinterpret_cast<const float4*>(base + h * DOUT + c0 + 4 * v);
    qq.x *= SCALE; qq.y *= SCALE; qq.z *= SCALE; qq.w *= SCALE;
    q[v] = qq;
    acc[v] = make_float4(0.f, 0.f, 0.f, 0.f);
  }
  const float g = G[(size_t)n * 64 + lane];  // G[n, h, d=t16], pre-scaled
  float m = -1e30f, lsum = 0.f, tacc = 0.f;

  const int s0 = offs[n], s1 = offs[n + 1];
  int ii = s0;

  for (; ii + 4 <= s1; ii += 4) {
    int sj[4];
#pragma unroll
    for (int j = 0; j < 4; ++j) sj[j] = csr_src[ii + j];
    float ea[4];
#pragma unroll
    for (int j = 0; j < 4; ++j) ea[j] = csr_ea[(size_t)(ii + j) * 16 + t16];
    float4 kj[4][NV], vj[4][NV];
#pragma unroll
    for (int j = 0; j < 4; ++j) {
      const float* rb = QKVS + (size_t)sj[j] * STRIDE + h * DOUT + c0;
#pragma unroll
      for (int v = 0; v < NV; ++v) {
        kj[j][v] = *reinterpret_cast<const float4*>(rb + HD + 4 * v);
        vj[j][v] = *reinterpret_cast<const float4*>(rb + 2 * HD + 4 * v);
      }
    }
    float a[4];
#pragma unroll
    for (int j = 0; j < 4; ++j) {
      float p = ea[j] * g;
#pragma unroll
      for (int v = 0; v < NV; ++v)
        p += q[v].x * kj[j][v].x + q[v].y * kj[j][v].y + q[v].z * kj[j][v].z +
             q[v].w * kj[j][v].w;
      a[j] = p;
    }
#pragma unroll
    for (int j = 0; j < 4; ++j) {
      a[j] += __shfl_xor(a[j], 1);
      a[j] += __shfl_xor(a[j], 2);
      a[j] += __shfl_xor(a[j], 4);
      a[j] += __shfl_xor(a[j], 8);
    }
    float mn = fmaxf(fmaxf(fmaxf(a[0], a[1]), fmaxf(a[2], a[3])), m);
    float fac = __expf(m - mn);
    float p0 = __expf(a[0] - mn), p1 = __expf(a[1] - mn);
    float p2 = __expf(a[2] - mn), p3 = __expf(a[3] - mn);
    m = mn;
    lsum = lsum * fac + (p0 + p1 + p2 + p3);
    tacc = tacc * fac + p0 * ea[0] + p1 * ea[1] + p2 * ea[2] + p3 * ea[3];
#pragma unroll
    for (int v = 0; v < NV; ++v) {
      float4 av = acc[v];
      av.x = av.x * fac + p0 * vj[0][v].x + p1 * vj[1][v].x + p2 * vj[2][v].x + p3 * vj[3][v].x;
      av.y = av.y * fac + p0 * vj[0][v].y + p1 * vj[1][v].y + p2 * vj[2][v].y + p3 * vj[3][v].y;
      av.z = av.z * fac + p0 * vj[0][v].z + p1 * vj[1][v].z + p2 * vj[2][v].z + p3 * vj[3][v].z;
      av.w = av.w * fac + p0 * vj[0][v].w + p1 * vj[1][v].w + p2 * vj[2][v].w + p3 * vj[3][v].w;
      acc[v] = av;
    }
  }

  for (; ii < s1; ++ii) {
    int s = csr_src[ii];
    float ea0 = csr_ea[(size_t)ii * 16 + t16];
    const float* rb = QKVS + (size_t)s * STRIDE + h * DOUT + c0;
    float4 kk[NV], vv[NV];
#pragma unroll
    for (int v = 0; v < NV; ++v) {
      kk[v] = *reinterpret_cast<const float4*>(rb + HD + 4 * v);
      vv[v] = *reinterpret_cast<const float4*>(rb + 2 * HD + 4 * v);
    }
    float a = ea0 * g;
#pragma unroll
    for (int v = 0; v < NV; ++v)
      a += q[v].x * kk[v].x + q[v].y * kk[v].y + q[v].z * kk[v].z + q[v].w * kk[v].w;
    a += __shfl_xor(a, 1);
    a += __shfl_xor(a, 2);
    a += __shfl_xor(a, 4);
    a += __shfl_xor(a, 8);
    float mn = fmaxf(m, a);
    float fac = __expf(m - mn);
    float p = __expf(a - mn);
    m = mn;
    lsum = lsum * fac + p;
    tacc = tacc * fac + p * ea0;
#pragma unroll
    for (int v = 0; v < NV; ++v) {
      acc[v].x = acc[v].x * fac + p * vv[v].x;
      acc[v].y = acc[v].y * fac + p * vv[v].y;
      acc[v].z = acc[v].z * fac + p * vv[v].z;
      acc[v].w = acc[v].w * fac + p * vv[v].w;
    }
  }

  // epilogue: normalize, add (sum attn·ea)@we, head mean, skip, ELU
  float invl = (lsum > 0.f) ? 1.f / lsum : 0.f;
  float tn = tacc * invl;
  float4 val[NV];
#pragma unroll
  for (int v = 0; v < NV; ++v) {
    val[v].x = acc[v].x * invl; val[v].y = acc[v].y * invl;
    val[v].z = acc[v].z * invl; val[v].w = acc[v].w * invl;
  }
#pragma unroll
  for (int d = 0; d < 16; ++d) {
    float td = __shfl(tn, (lane & 48) | d);
    const float* wb = we_s + d * HD + h * DOUT + c0;
#pragma unroll
    for (int v = 0; v < NV; ++v) {
      float4 w4 = *reinterpret_cast<const float4*>(wb + 4 * v);
      val[v].x += td * w4.x; val[v].y += td * w4.y;
      val[v].z += td * w4.z; val[v].w += td * w4.w;
    }
  }
  // head mean across the 4 groups
#pragma unroll
  for (int v = 0; v < NV; ++v) {
    val[v].x += __shfl_xor(val[v].x, 16); val[v].x += __shfl_xor(val[v].x, 32);
    val[v].y += __shfl_xor(val[v].y, 16); val[v].y += __shfl_xor(val[v].y, 32);
    val[v].z += __shfl_xor(val[v].z, 16); val[v].z += __shfl_xor(val[v].z, 32);
    val[v].w += __shfl_xor(val[v].w, 16); val[v].w += __shfl_xor(val[v].w, 32);
  }
  if (h == 0) {
#pragma unroll
    for (int v = 0; v < NV; ++v) {
      float4 sk = *reinterpret_cast<const float4*>(base + 3 * HD + c0 + 4 * v);
      float4 o;
      o.x = 0.25f * val[v].x + sk.x;
      o.y = 0.25f * val[v].y + sk.y;
      o.z = 0.25f * val[v].z + sk.z;
      o.w = 0.25f * val[v].w + sk.w;
      o.x = (o.x > 0.f) ? o.x : expm1f(o.x);
      o.y = (o.y > 0.f) ? o.y : expm1f(o.y);
      o.z = (o.z > 0.f) ? o.z : expm1f(o.z);
      o.w = (o.w > 0.f) ? o.w : expm1f(o.w);
      *reinterpret_cast<float4*>(out + (size_t)n * DOUT + c0 + 4 * v) = o;
    }
  }
}

// ---------------------------------------------------------------------------
// Global mean pool over graphs
// ---------------------------------------------------------------------------
__global__ void pool_zero(float* __restrict__ out, int* __restrict__ gcnt) {
  int i = blockIdx.x * blockDim.x + threadIdx.x;
  if (i < N_GRAPHS * 64) out[i] = 0.f;
  if (i < N_GRAPHS) gcnt[i] = 0;
}

__global__ void pool_acc(const float* __restrict__ h, const int* __restrict__ batch,
                         float* __restrict__ out, int* __restrict__ gcnt) {
  int i = blockIdx.x * blockDim.x + threadIdx.x;
  if (i >= N_NODES * 64) return;
  int n = i >> 6, c = i & 63;
  int g = batch[n];
  atomicAdd(&out[g * 64 + c], h[(size_t)n * 64 + c]);
  if (c == 0) atomicAdd(&gcnt[g], 1);
}

__global__ void pool_div(float* __restrict__ out, const int* __restrict__ gcnt) {
  int i = blockIdx.x * blockDim.x + threadIdx.x;
  if (i < N_GRAPHS * 64) out[i] /= (float)max(gcnt[i >> 6], 1);
}

// ---------------------------------------------------------------------------
extern "C" void kernel_launch(void* const* d_in, const int* in_sizes, int n_in,
                              void* d_out, int out_size, void* d_ws, size_t ws_size,
                              hipStream_t stream) {
  const float* x = (const float*)d_in[0];
  const int* edge_index = (const int*)d_in[1];
  const float* edge_attr = (const float*)d_in[2];
  const int* batch = (const int*)d_in[3];
  const int* srcp = edge_index;            // edge_index[0]
  const int* dstp = edge_index + N_EDGES;  // edge_index[1]

  const bool dict_order = in_sizes[5] > 1024;
  const float *wq[3], *wk[3], *wv[3], *wep[3], *wsk[3], *bq[3], *bk[3], *bv[3], *bs[3];
  for (int L = 0; L < 3; ++L) {
    int b = 4 + L * 9;
    if (dict_order) {
      wq[L] = (const float*)d_in[b + 0];
      wk[L] = (const float*)d_in[b + 1];
      wv[L] = (const float*)d_in[b + 2];
      wep[L] = (const float*)d_in[b + 3];
      wsk[L] = (const float*)d_in[b + 4];
      bq[L] = (const float*)d_in[b + 5];
      bk[L] = (const float*)d_in[b + 6];
      bv[L] = (const float*)d_in[b + 7];
      bs[L] = (const float*)d_in[b + 8];
    } else {
      wq[L] = (const float*)d_in[b + 0];
      bq[L] = (const float*)d_in[b + 1];
      wk[L] = (const float*)d_in[b + 2];
      bk[L] = (const float*)d_in[b + 3];
      wv[L] = (const float*)d_in[b + 4];
      bv[L] = (const float*)d_in[b + 5];
      wep[L] = (const float*)d_in[b + 6];
      wsk[L] = (const float*)d_in[b + 7];
      bs[L] = (const float*)d_in[b + 8];
    }
  }

  // Workspace carve.
  float* qkvs = (float*)d_ws;                    // N * 1664 max
  float* h1 = qkvs + (size_t)N_NODES * 1664;     // N * 128
  float* h2 = h1 + (size_t)N_NODES * 128;        // N * 128
  float* Wcat = h2 + (size_t)N_NODES * 128;      // 128 * 1664 max
  float* bcat = Wcat + 128 * 1664;               // 2048
  float* Gbuf = bcat + 2048;                     // N * 64
  float* csr_ea = Gbuf + (size_t)N_NODES * 64;   // E * 16
  int* cnt = (int*)(csr_ea + (size_t)N_EDGES * 16);  // N
  int* cursor = cnt + N_NODES;                   // N
  int* offs = cursor + N_NODES;                  // N + 1
  int* csr_src = offs + N_NODES + 1;             // E
  int* gcnt = csr_src + N_EDGES;                 // 64

  // ---- CSR build over dst (same for all layers) ----
  zero_ints<<<79, 256, 0, stream>>>(cnt, 2 * N_NODES);  // cnt + cursor
  count_dst<<<(N_EDGES + 255) / 256, 256, 0, stream>>>(dstp, cnt);
  scan_offs<<<1, 256, 0, stream>>>(cnt, offs);
  scatter_csr<<<(N_EDGES + 255) / 256, 256, 0, stream>>>(srcp, dstp, edge_attr,
                                                         offs, cursor, csr_src, csr_ea);

  // ---- 3 TransformerConv layers ----
  const int Kdim[3] = {128, 64, 128};
  const int Dout[3] = {64, 128, 64};
  const float* hin = x;
  float* hout[3] = {h1, h2, h1};

  for (int L = 0; L < 3; ++L) {
    const int K = Kdim[L], DOUT = Dout[L], HD = 4 * DOUT, W = 3 * HD + DOUT;
    pack_w<<<((K + 1) * W + 255) / 256, 256, 0, stream>>>(
        wq[L], wk[L], wv[L], wsk[L], bq[L], bk[L], bv[L], bs[L], Wcat, bcat, K, HD, DOUT);
    dim3 ggrid(W / 64, (N_NODES + 63) / 64);
    if (K == 128)
      gemm_bias<128><<<ggrid, 256, 0, stream>>>(hin, Wcat, bcat, qkvs, N_NODES, W);
    else
      gemm_bias<64><<<ggrid, 256, 0, stream>>>(hin, Wcat, bcat, qkvs, N_NODES, W);
    if (DOUT == 64) {
      g_precompute<64><<<N_NODES / 4, 256, 0, stream>>>(qkvs, wep[L], Gbuf);
      edge_attn<64><<<N_NODES / 4, 256, 0, stream>>>(qkvs, wep[L], Gbuf, csr_src,
                                                     csr_ea, offs, hout[L]);
    } else {
      g_precompute<128><<<N_NODES / 4, 256, 0, stream>>>(qkvs, wep[L], Gbuf);
      edge_attn<128><<<N_NODES / 4, 256, 0, stream>>>(qkvs, wep[L], Gbuf, csr_src,
                                                      csr_ea, offs, hout[L]);
    }
    hin = hout[L];
  }

  // ---- global mean pool ----
  pool_zero<<<17, 256, 0, stream>>>((float*)d_out, gcnt);
  pool_acc<<<(N_NODES * 64 + 255) / 256, 256, 0, stream>>>(h1, batch, (float*)d_out, gcnt);
  pool_div<<<16, 256, 0, stream>>>((float*)d_out, gcnt);
}

// Round 3
// 561.239 us; speedup vs baseline: 1.4928x; 1.1415x over previous
//
#include <hip/hip_runtime.h>
#include <math.h>

#define N_NODES 10000
#define N_EDGES 160000
#define N_GRAPHS 64

// ---------------------------------------------------------------------------
// Fused GEMM: C[M,W] = A[M,K] @ B[K,W] + bias[W]
// 64x64 block tile, 256 threads, 4x4 per thread, K staged in 32-chunks
// (17 KB LDS -> ~5 blocks/CU instead of 2 with full-K staging).
// ---------------------------------------------------------------------------
template <int K>
__global__ __launch_bounds__(256) void gemm_bias(
    const float* __restrict__ A, const float* __restrict__ B,
    const float* __restrict__ bias, float* __restrict__ C, int M, int W) {
  __shared__ float Ast[32][68];  // [k][m] (A transposed in LDS)
  __shared__ float Bs[32][68];   // [k][n]
  const int tid = threadIdx.x;
  const int tx = tid & 15, ty = tid >> 4;
  const int row0 = blockIdx.y * 64, col0 = blockIdx.x * 64;

  float acc[4][4] = {};
  for (int k0 = 0; k0 < K; k0 += 32) {
    for (int i = tid; i < 2048; i += 256) {
      int r = i >> 5, c = i & 31;  // consecutive i -> consecutive c (128B/row)
      int gr = row0 + r;
      Ast[c][r] = (gr < M) ? A[(size_t)gr * K + k0 + c] : 0.f;
    }
    for (int i = tid; i < 2048; i += 256) {
      int r = i >> 6, c = i & 63;  // coalesced B read (W multiple of 64)
      Bs[r][c] = B[(size_t)(k0 + r) * W + col0 + c];
    }
    __syncthreads();
#pragma unroll
    for (int k = 0; k < 32; ++k) {
      float4 a4 = *reinterpret_cast<const float4*>(&Ast[k][ty * 4]);
      float4 b4 = *reinterpret_cast<const float4*>(&Bs[k][tx * 4]);
      float a[4] = {a4.x, a4.y, a4.z, a4.w};
      float b[4] = {b4.x, b4.y, b4.z, b4.w};
#pragma unroll
      for (int m_ = 0; m_ < 4; ++m_)
#pragma unroll
        for (int n_ = 0; n_ < 4; ++n_) acc[m_][n_] += a[m_] * b[n_];
    }
    __syncthreads();
  }

  float bb[4];
#pragma unroll
  for (int n_ = 0; n_ < 4; ++n_) bb[n_] = bias[col0 + tx * 4 + n_];
#pragma unroll
  for (int m_ = 0; m_ < 4; ++m_) {
    int gr = row0 + ty * 4 + m_;
    if (gr < M) {
      float4 o;
      o.x = acc[m_][0] + bb[0];
      o.y = acc[m_][1] + bb[1];
      o.z = acc[m_][2] + bb[2];
      o.w = acc[m_][3] + bb[3];
      *reinterpret_cast<float4*>(C + (size_t)gr * W + col0 + tx * 4) = o;
    }
  }
}

// ---------------------------------------------------------------------------
// Weight/bias concat pack: Wcat[K][3*HD+DOUT] = [wq|wk|wv|ws], bcat likewise.
// ---------------------------------------------------------------------------
__global__ void pack_w(const float* __restrict__ wq, const float* __restrict__ wk,
                       const float* __restrict__ wv, const float* __restrict__ wsk,
                       const float* __restrict__ bq, const float* __restrict__ bk,
                       const float* __restrict__ bv, const float* __restrict__ bs,
                       float* __restrict__ Wcat, float* __restrict__ bcat,
                       int K, int HD, int DOUT) {
  const int W = 3 * HD + DOUT;
  const int total = (K + 1) * W;
  for (int i = blockIdx.x * blockDim.x + threadIdx.x; i < total;
       i += gridDim.x * blockDim.x) {
    int k = i / W, j = i % W;
    float v;
    if (j < HD)           v = (k < K) ? wq[k * HD + j]             : bq[j];
    else if (j < 2 * HD)  v = (k < K) ? wk[k * HD + (j - HD)]      : bk[j - HD];
    else if (j < 3 * HD)  v = (k < K) ? wv[k * HD + (j - 2 * HD)]  : bv[j - 2 * HD];
    else                  v = (k < K) ? wsk[k * DOUT + (j - 3 * HD)] : bs[j - 3 * HD];
    if (k < K) Wcat[i] = v; else bcat[j] = v;
  }
}

// ---------------------------------------------------------------------------
// CSR build over dst (+ permute src and edge_attr into CSR order)
// ---------------------------------------------------------------------------
__global__ void zero_ints(int* __restrict__ a, int n) {
  for (int i = blockIdx.x * blockDim.x + threadIdx.x; i < n;
       i += gridDim.x * blockDim.x) a[i] = 0;
}

__global__ void count_dst(const int* __restrict__ dst, int* __restrict__ cnt) {
  int e = blockIdx.x * blockDim.x + threadIdx.x;
  if (e < N_EDGES) atomicAdd(&cnt[dst[e]], 1);
}

__global__ __launch_bounds__(256) void scan_offs(const int* __restrict__ cnt,
                                                 int* __restrict__ offs) {
  __shared__ int part[256];
  const int t = threadIdx.x;
  const int chunk = (N_NODES + 255) / 256;
  const int b = t * chunk;
  const int e = min(N_NODES, b + chunk);
  int s = 0;
  for (int i = b; i < e; ++i) s += cnt[i];
  part[t] = s;
  __syncthreads();
  for (int off = 1; off < 256; off <<= 1) {
    int v = (t >= off) ? part[t - off] : 0;
    __syncthreads();
    part[t] += v;
    __syncthreads();
  }
  int pre = (t == 0) ? 0 : part[t - 1];
  for (int i = b; i < e; ++i) { offs[i] = pre; pre += cnt[i]; }
  if (t == 0) offs[N_NODES] = part[255];
}

__global__ void scatter_csr(const int* __restrict__ src, const int* __restrict__ dst,
                            const float* __restrict__ edge_attr,
                            const int* __restrict__ offs, int* __restrict__ cursor,
                            int* __restrict__ csr_src, float* __restrict__ csr_ea) {
  int e = blockIdx.x * blockDim.x + threadIdx.x;
  if (e < N_EDGES) {
    int d = dst[e];
    int pos = offs[d] + atomicAdd(&cursor[d], 1);
    csr_src[pos] = src[e];
    float4* o4 = reinterpret_cast<float4*>(csr_ea + (size_t)pos * 16);
    const float4* s4 = reinterpret_cast<const float4*>(edge_attr + (size_t)e * 16);
    o4[0] = s4[0]; o4[1] = s4[1]; o4[2] = s4[2]; o4[3] = s4[3];
  }
}

// ---------------------------------------------------------------------------
// Fused edge kernel, head-local lanes + folded edge-feature algebra.
// alpha[e,h] = SCALE*(q[dst,h]·k[src,h]) + ea[e]·G[dst,h]
//   with G[n,h,d] = SCALE * sum_c q[n,h,c]·we[d,h*DOUT+c]  (computed inline)
// agg[h]    = sum attn·v[src,h]  +  (sum attn·ea) @ we[:,h,:]
// Lane l: head h=l>>4, channels c0 = (l&15)*4*NV .. +4*NV-1.
// NO LDS: `we` is read from global (L1/L2-hot, touched only per-node).
// ---------------------------------------------------------------------------
template <int DOUT>
__global__ __launch_bounds__(256) void edge_attn(
    const float* __restrict__ QKVS, const float* __restrict__ we,
    const int* __restrict__ csr_src, const float* __restrict__ csr_ea,
    const int* __restrict__ offs, float* __restrict__ out) {
  constexpr int HD = 4 * DOUT;
  constexpr int STRIDE = 3 * HD + DOUT;
  constexpr int NV = DOUT / 64;
  const float SCALE = (DOUT == 64) ? 0.125f : 0.08838834764831845f;

  const int lane = threadIdx.x & 63;
  const int h = lane >> 4, t16 = lane & 15;
  const int n = blockIdx.x * 4 + (threadIdx.x >> 6);  // N_NODES % 4 == 0
  const int c0 = t16 * 4 * NV;

  const float* base = QKVS + (size_t)n * STRIDE;
  float4 q[NV], acc[NV];
#pragma unroll
  for (int v = 0; v < NV; ++v) {
    float4 qq = *reinterpret_cast<const float4*>(base + h * DOUT + c0 + 4 * v);
    qq.x *= SCALE; qq.y *= SCALE; qq.z *= SCALE; qq.w *= SCALE;
    q[v] = qq;
    acc[v] = make_float4(0.f, 0.f, 0.f, 0.f);
  }

  // inline G: g = SCALE * sum_c q[h,c]·we[d, h*DOUT+c], kept by lane t16==d
  float g = 0.f;
#pragma unroll
  for (int d = 0; d < 16; ++d) {
    float p = 0.f;
    const float* wb = we + d * HD + h * DOUT + c0;
#pragma unroll
    for (int v = 0; v < NV; ++v) {
      float4 w4 = *reinterpret_cast<const float4*>(wb + 4 * v);
      p += q[v].x * w4.x + q[v].y * w4.y + q[v].z * w4.z + q[v].w * w4.w;
    }
    p += __shfl_xor(p, 1);
    p += __shfl_xor(p, 2);
    p += __shfl_xor(p, 4);
    p += __shfl_xor(p, 8);
    if (t16 == d) g = p;
  }

  float m = -1e30f, lsum = 0.f, tacc = 0.f;

  const int s0 = offs[n], s1 = offs[n + 1];
  int ii = s0;

  for (; ii + 4 <= s1; ii += 4) {
    int sj[4];
#pragma unroll
    for (int j = 0; j < 4; ++j) sj[j] = csr_src[ii + j];
    float ea[4];
#pragma unroll
    for (int j = 0; j < 4; ++j) ea[j] = csr_ea[(size_t)(ii + j) * 16 + t16];
    float4 kj[4][NV], vj[4][NV];
#pragma unroll
    for (int j = 0; j < 4; ++j) {
      const float* rb = QKVS + (size_t)sj[j] * STRIDE + h * DOUT + c0;
#pragma unroll
      for (int v = 0; v < NV; ++v) {
        kj[j][v] = *reinterpret_cast<const float4*>(rb + HD + 4 * v);
        vj[j][v] = *reinterpret_cast<const float4*>(rb + 2 * HD + 4 * v);
      }
    }
    float a[4];
#pragma unroll
    for (int j = 0; j < 4; ++j) {
      float p = ea[j] * g;
#pragma unroll
      for (int v = 0; v < NV; ++v)
        p += q[v].x * kj[j][v].x + q[v].y * kj[j][v].y + q[v].z * kj[j][v].z +
             q[v].w * kj[j][v].w;
      a[j] = p;
    }
#pragma unroll
    for (int j = 0; j < 4; ++j) {
      a[j] += __shfl_xor(a[j], 1);
      a[j] += __shfl_xor(a[j], 2);
      a[j] += __shfl_xor(a[j], 4);
      a[j] += __shfl_xor(a[j], 8);
    }
    float mn = fmaxf(fmaxf(fmaxf(a[0], a[1]), fmaxf(a[2], a[3])), m);
    float fac = __expf(m - mn);
    float p0 = __expf(a[0] - mn), p1 = __expf(a[1] - mn);
    float p2 = __expf(a[2] - mn), p3 = __expf(a[3] - mn);
    m = mn;
    lsum = lsum * fac + (p0 + p1 + p2 + p3);
    tacc = tacc * fac + p0 * ea[0] + p1 * ea[1] + p2 * ea[2] + p3 * ea[3];
#pragma unroll
    for (int v = 0; v < NV; ++v) {
      float4 av = acc[v];
      av.x = av.x * fac + p0 * vj[0][v].x + p1 * vj[1][v].x + p2 * vj[2][v].x + p3 * vj[3][v].x;
      av.y = av.y * fac + p0 * vj[0][v].y + p1 * vj[1][v].y + p2 * vj[2][v].y + p3 * vj[3][v].y;
      av.z = av.z * fac + p0 * vj[0][v].z + p1 * vj[1][v].z + p2 * vj[2][v].z + p3 * vj[3][v].z;
      av.w = av.w * fac + p0 * vj[0][v].w + p1 * vj[1][v].w + p2 * vj[2][v].w + p3 * vj[3][v].w;
      acc[v] = av;
    }
  }

  for (; ii < s1; ++ii) {
    int s = csr_src[ii];
    float ea0 = csr_ea[(size_t)ii * 16 + t16];
    const float* rb = QKVS + (size_t)s * STRIDE + h * DOUT + c0;
    float4 kk[NV], vv[NV];
#pragma unroll
    for (int v = 0; v < NV; ++v) {
      kk[v] = *reinterpret_cast<const float4*>(rb + HD + 4 * v);
      vv[v] = *reinterpret_cast<const float4*>(rb + 2 * HD + 4 * v);
    }
    float a = ea0 * g;
#pragma unroll
    for (int v = 0; v < NV; ++v)
      a += q[v].x * kk[v].x + q[v].y * kk[v].y + q[v].z * kk[v].z + q[v].w * kk[v].w;
    a += __shfl_xor(a, 1);
    a += __shfl_xor(a, 2);
    a += __shfl_xor(a, 4);
    a += __shfl_xor(a, 8);
    float mn = fmaxf(m, a);
    float fac = __expf(m - mn);
    float p = __expf(a - mn);
    m = mn;
    lsum = lsum * fac + p;
    tacc = tacc * fac + p * ea0;
#pragma unroll
    for (int v = 0; v < NV; ++v) {
      acc[v].x = acc[v].x * fac + p * vv[v].x;
      acc[v].y = acc[v].y * fac + p * vv[v].y;
      acc[v].z = acc[v].z * fac + p * vv[v].z;
      acc[v].w = acc[v].w * fac + p * vv[v].w;
    }
  }

  // epilogue: normalize, add (sum attn·ea)@we, head mean, skip, ELU
  float invl = (lsum > 0.f) ? 1.f / lsum : 0.f;
  float tn = tacc * invl;
  float4 val[NV];
#pragma unroll
  for (int v = 0; v < NV; ++v) {
    val[v].x = acc[v].x * invl; val[v].y = acc[v].y * invl;
    val[v].z = acc[v].z * invl; val[v].w = acc[v].w * invl;
  }
#pragma unroll
  for (int d = 0; d < 16; ++d) {
    float td = __shfl(tn, (lane & 48) | d);
    const float* wb = we + d * HD + h * DOUT + c0;
#pragma unroll
    for (int v = 0; v < NV; ++v) {
      float4 w4 = *reinterpret_cast<const float4*>(wb + 4 * v);
      val[v].x += td * w4.x; val[v].y += td * w4.y;
      val[v].z += td * w4.z; val[v].w += td * w4.w;
    }
  }
  // head mean across the 4 groups
#pragma unroll
  for (int v = 0; v < NV; ++v) {
    val[v].x += __shfl_xor(val[v].x, 16); val[v].x += __shfl_xor(val[v].x, 32);
    val[v].y += __shfl_xor(val[v].y, 16); val[v].y += __shfl_xor(val[v].y, 32);
    val[v].z += __shfl_xor(val[v].z, 16); val[v].z += __shfl_xor(val[v].z, 32);
    val[v].w += __shfl_xor(val[v].w, 16); val[v].w += __shfl_xor(val[v].w, 32);
  }
  if (h == 0) {
#pragma unroll
    for (int v = 0; v < NV; ++v) {
      float4 sk = *reinterpret_cast<const float4*>(base + 3 * HD + c0 + 4 * v);
      float4 o;
      o.x = 0.25f * val[v].x + sk.x;
      o.y = 0.25f * val[v].y + sk.y;
      o.z = 0.25f * val[v].z + sk.z;
      o.w = 0.25f * val[v].w + sk.w;
      o.x = (o.x > 0.f) ? o.x : expm1f(o.x);
      o.y = (o.y > 0.f) ? o.y : expm1f(o.y);
      o.z = (o.z > 0.f) ? o.z : expm1f(o.z);
      o.w = (o.w > 0.f) ? o.w : expm1f(o.w);
      *reinterpret_cast<float4*>(out + (size_t)n * DOUT + c0 + 4 * v) = o;
    }
  }
}

// ---------------------------------------------------------------------------
// Global mean pool over graphs
// ---------------------------------------------------------------------------
__global__ void pool_zero(float* __restrict__ out, int* __restrict__ gcnt) {
  int i = blockIdx.x * blockDim.x + threadIdx.x;
  if (i < N_GRAPHS * 64) out[i] = 0.f;
  if (i < N_GRAPHS) gcnt[i] = 0;
}

__global__ void pool_acc(const float* __restrict__ h, const int* __restrict__ batch,
                         float* __restrict__ out, int* __restrict__ gcnt) {
  int i = blockIdx.x * blockDim.x + threadIdx.x;
  if (i >= N_NODES * 64) return;
  int n = i >> 6, c = i & 63;
  int g = batch[n];
  atomicAdd(&out[g * 64 + c], h[(size_t)n * 64 + c]);
  if (c == 0) atomicAdd(&gcnt[g], 1);
}

__global__ void pool_div(float* __restrict__ out, const int* __restrict__ gcnt) {
  int i = blockIdx.x * blockDim.x + threadIdx.x;
  if (i < N_GRAPHS * 64) out[i] /= (float)max(gcnt[i >> 6], 1);
}

// ---------------------------------------------------------------------------
extern "C" void kernel_launch(void* const* d_in, const int* in_sizes, int n_in,
                              void* d_out, int out_size, void* d_ws, size_t ws_size,
                              hipStream_t stream) {
  const float* x = (const float*)d_in[0];
  const int* edge_index = (const int*)d_in[1];
  const float* edge_attr = (const float*)d_in[2];
  const int* batch = (const int*)d_in[3];
  const int* srcp = edge_index;            // edge_index[0]
  const int* dstp = edge_index + N_EDGES;  // edge_index[1]

  const bool dict_order = in_sizes[5] > 1024;
  const float *wq[3], *wk[3], *wv[3], *wep[3], *wsk[3], *bq[3], *bk[3], *bv[3], *bs[3];
  for (int L = 0; L < 3; ++L) {
    int b = 4 + L * 9;
    if (dict_order) {
      wq[L] = (const float*)d_in[b + 0];
      wk[L] = (const float*)d_in[b + 1];
      wv[L] = (const float*)d_in[b + 2];
      wep[L] = (const float*)d_in[b + 3];
      wsk[L] = (const float*)d_in[b + 4];
      bq[L] = (const float*)d_in[b + 5];
      bk[L] = (const float*)d_in[b + 6];
      bv[L] = (const float*)d_in[b + 7];
      bs[L] = (const float*)d_in[b + 8];
    } else {
      wq[L] = (const float*)d_in[b + 0];
      bq[L] = (const float*)d_in[b + 1];
      wk[L] = (const float*)d_in[b + 2];
      bk[L] = (const float*)d_in[b + 3];
      wv[L] = (const float*)d_in[b + 4];
      bv[L] = (const float*)d_in[b + 5];
      wep[L] = (const float*)d_in[b + 6];
      wsk[L] = (const float*)d_in[b + 7];
      bs[L] = (const float*)d_in[b + 8];
    }
  }

  // Workspace carve.
  float* qkvs = (float*)d_ws;                    // N * 1664 max
  float* h1 = qkvs + (size_t)N_NODES * 1664;     // N * 128
  float* h2 = h1 + (size_t)N_NODES * 128;        // N * 128
  float* Wcat = h2 + (size_t)N_NODES * 128;      // 128 * 1664 max
  float* bcat = Wcat + 128 * 1664;               // 2048
  float* csr_ea = bcat + 2048;                   // E * 16
  int* cnt = (int*)(csr_ea + (size_t)N_EDGES * 16);  // N
  int* cursor = cnt + N_NODES;                   // N
  int* offs = cursor + N_NODES;                  // N + 1
  int* csr_src = offs + N_NODES + 1;             // E
  int* gcnt = csr_src + N_EDGES;                 // 64

  // ---- CSR build over dst (same for all layers) ----
  zero_ints<<<79, 256, 0, stream>>>(cnt, 2 * N_NODES);  // cnt + cursor
  count_dst<<<(N_EDGES + 255) / 256, 256, 0, stream>>>(dstp, cnt);
  scan_offs<<<1, 256, 0, stream>>>(cnt, offs);
  scatter_csr<<<(N_EDGES + 255) / 256, 256, 0, stream>>>(srcp, dstp, edge_attr,
                                                         offs, cursor, csr_src, csr_ea);

  // ---- 3 TransformerConv layers ----
  const int Kdim[3] = {128, 64, 128};
  const int Dout[3] = {64, 128, 64};
  const float* hin = x;
  float* hout[3] = {h1, h2, h1};

  for (int L = 0; L < 3; ++L) {
    const int K = Kdim[L], DOUT = Dout[L], HD = 4 * DOUT, W = 3 * HD + DOUT;
    pack_w<<<((K + 1) * W + 255) / 256, 256, 0, stream>>>(
        wq[L], wk[L], wv[L], wsk[L], bq[L], bk[L], bv[L], bs[L], Wcat, bcat, K, HD, DOUT);
    dim3 ggrid(W / 64, (N_NODES + 63) / 64);
    if (K == 128)
      gemm_bias<128><<<ggrid, 256, 0, stream>>>(hin, Wcat, bcat, qkvs, N_NODES, W);
    else
      gemm_bias<64><<<ggrid, 256, 0, stream>>>(hin, Wcat, bcat, qkvs, N_NODES, W);
    if (DOUT == 64)
      edge_attn<64><<<N_NODES / 4, 256, 0, stream>>>(qkvs, wep[L], csr_src,
                                                     csr_ea, offs, hout[L]);
    else
      edge_attn<128><<<N_NODES / 4, 256, 0, stream>>>(qkvs, wep[L], csr_src,
                                                      csr_ea, offs, hout[L]);
    hin = hout[L];
  }

  // ---- global mean pool ----
  pool_zero<<<17, 256, 0, stream>>>((float*)d_out, gcnt);
  pool_acc<<<(N_NODES * 64 + 255) / 256, 256, 0, stream>>>(h1, batch, (float*)d_out, gcnt);
  pool_div<<<16, 256, 0, stream>>>((float*)d_out, gcnt);
}

// Round 4
// 451.651 us; speedup vs baseline: 1.8550x; 1.2426x over previous
//
#include <hip/hip_runtime.h>
#include <hip/hip_fp16.h>
#include <math.h>

#define N_NODES 10000
#define N_EDGES 160000
#define N_GRAPHS 64

// ---------------------------------------------------------------------------
// Fused GEMM: [Q|K|V|S] = A[M,K] @ Wcat[K,W] + bcat.  Output split:
//   cols [0,HD)      -> QS f32 buffer at [0,HD)      (row stride HD+DOUT)
//   cols [HD,3HD)    -> KV __half buffer              (row stride 2*HD)
//   cols [3HD,W)     -> QS f32 buffer at [HD,HD+DOUT)
// 64x64 tile, 256 threads, 4x4/thread, K staged in 32-chunks (17 KB LDS).
// ---------------------------------------------------------------------------
template <int K, int HD, int DOUT>
__global__ __launch_bounds__(256) void gemm_bias(
    const float* __restrict__ A, const float* __restrict__ B,
    const float* __restrict__ bias, float* __restrict__ QS,
    __half* __restrict__ KV, int M) {
  constexpr int W = 3 * HD + DOUT;
  constexpr int QSS = HD + DOUT;
  __shared__ float Ast[32][68];  // [k][m]
  __shared__ float Bs[32][68];   // [k][n]
  const int tid = threadIdx.x;
  const int tx = tid & 15, ty = tid >> 4;
  const int row0 = blockIdx.y * 64, col0 = blockIdx.x * 64;

  float acc[4][4] = {};
  for (int k0 = 0; k0 < K; k0 += 32) {
    for (int i = tid; i < 2048; i += 256) {
      int r = i >> 5, c = i & 31;
      int gr = row0 + r;
      Ast[c][r] = (gr < M) ? A[(size_t)gr * K + k0 + c] : 0.f;
    }
    for (int i = tid; i < 2048; i += 256) {
      int r = i >> 6, c = i & 63;
      Bs[r][c] = B[(size_t)(k0 + r) * W + col0 + c];
    }
    __syncthreads();
#pragma unroll
    for (int k = 0; k < 32; ++k) {
      float4 a4 = *reinterpret_cast<const float4*>(&Ast[k][ty * 4]);
      float4 b4 = *reinterpret_cast<const float4*>(&Bs[k][tx * 4]);
      float a[4] = {a4.x, a4.y, a4.z, a4.w};
      float b[4] = {b4.x, b4.y, b4.z, b4.w};
#pragma unroll
      for (int m_ = 0; m_ < 4; ++m_)
#pragma unroll
        for (int n_ = 0; n_ < 4; ++n_) acc[m_][n_] += a[m_] * b[n_];
    }
    __syncthreads();
  }

  float bb[4];
#pragma unroll
  for (int n_ = 0; n_ < 4; ++n_) bb[n_] = bias[col0 + tx * 4 + n_];
#pragma unroll
  for (int m_ = 0; m_ < 4; ++m_) {
    int gr = row0 + ty * 4 + m_;
    if (gr < M) {
      float4 o;
      o.x = acc[m_][0] + bb[0];
      o.y = acc[m_][1] + bb[1];
      o.z = acc[m_][2] + bb[2];
      o.w = acc[m_][3] + bb[3];
      if (col0 < HD) {
        *reinterpret_cast<float4*>(QS + (size_t)gr * QSS + col0 + tx * 4) = o;
      } else if (col0 < 3 * HD) {
        __half* kp = KV + (size_t)gr * (2 * HD) + (col0 - HD) + tx * 4;
        reinterpret_cast<__half2*>(kp)[0] = __floats2half2_rn(o.x, o.y);
        reinterpret_cast<__half2*>(kp)[1] = __floats2half2_rn(o.z, o.w);
      } else {
        *reinterpret_cast<float4*>(QS + (size_t)gr * QSS + HD + (col0 - 3 * HD) +
                                   tx * 4) = o;
      }
    }
  }
}

// ---------------------------------------------------------------------------
// Pack all 3 layers' weights/biases in ONE launch.
// ---------------------------------------------------------------------------
__device__ inline void pack_one(int i, int K, int HD, int DOUT,
                                const float* wq, const float* wk,
                                const float* wv, const float* wsk,
                                const float* bq, const float* bk,
                                const float* bv, const float* bs,
                                float* Wcat, float* bcat) {
  const int W = 3 * HD + DOUT;
  int k = i / W, j = i % W;
  float v;
  if (j < HD)           v = (k < K) ? wq[k * HD + j]              : bq[j];
  else if (j < 2 * HD)  v = (k < K) ? wk[k * HD + (j - HD)]       : bk[j - HD];
  else if (j < 3 * HD)  v = (k < K) ? wv[k * HD + (j - 2 * HD)]   : bv[j - 2 * HD];
  else                  v = (k < K) ? wsk[k * DOUT + (j - 3 * HD)] : bs[j - 3 * HD];
  if (k < K) Wcat[i] = v; else bcat[j] = v;
}

#define S1 107328   // (128+1)*832
#define S2 215488   // S1 + (64+1)*1664
#define S3 322816   // S2 + (128+1)*832

__global__ void pack_all(
    const float* wq1, const float* wk1, const float* wv1, const float* ws1,
    const float* bq1, const float* bk1, const float* bv1, const float* bs1,
    const float* wq2, const float* wk2, const float* wv2, const float* ws2,
    const float* bq2, const float* bk2, const float* bv2, const float* bs2,
    const float* wq3, const float* wk3, const float* wv3, const float* ws3,
    const float* bq3, const float* bk3, const float* bv3, const float* bs3,
    float* W1, float* b1, float* W2, float* b2, float* W3, float* b3) {
  for (int i = blockIdx.x * blockDim.x + threadIdx.x; i < S3;
       i += gridDim.x * blockDim.x) {
    if (i < S1)
      pack_one(i, 128, 256, 64, wq1, wk1, wv1, ws1, bq1, bk1, bv1, bs1, W1, b1);
    else if (i < S2)
      pack_one(i - S1, 64, 512, 128, wq2, wk2, wv2, ws2, bq2, bk2, bv2, bs2, W2, b2);
    else
      pack_one(i - S2, 128, 256, 64, wq3, wk3, wv3, ws3, bq3, bk3, bv3, bs3, W3, b3);
  }
}

// ---------------------------------------------------------------------------
// CSR build over dst (+ permute src and edge_attr into CSR order)
// ---------------------------------------------------------------------------
__global__ void zero_ints(int* __restrict__ a, int n) {
  for (int i = blockIdx.x * blockDim.x + threadIdx.x; i < n;
       i += gridDim.x * blockDim.x) a[i] = 0;
}

__global__ void count_dst(const int* __restrict__ dst, int* __restrict__ cnt) {
  int e = blockIdx.x * blockDim.x + threadIdx.x;
  if (e < N_EDGES) atomicAdd(&cnt[dst[e]], 1);
}

__global__ __launch_bounds__(256) void scan_offs(const int* __restrict__ cnt,
                                                 int* __restrict__ offs) {
  __shared__ int part[256];
  const int t = threadIdx.x;
  const int chunk = (N_NODES + 255) / 256;
  const int b = t * chunk;
  const int e = min(N_NODES, b + chunk);
  int s = 0;
  for (int i = b; i < e; ++i) s += cnt[i];
  part[t] = s;
  __syncthreads();
  for (int off = 1; off < 256; off <<= 1) {
    int v = (t >= off) ? part[t - off] : 0;
    __syncthreads();
    part[t] += v;
    __syncthreads();
  }
  int pre = (t == 0) ? 0 : part[t - 1];
  for (int i = b; i < e; ++i) { offs[i] = pre; pre += cnt[i]; }
  if (t == 0) offs[N_NODES] = part[255];
}

__global__ void scatter_csr(const int* __restrict__ src, const int* __restrict__ dst,
                            const float* __restrict__ edge_attr,
                            const int* __restrict__ offs, int* __restrict__ cursor,
                            int* __restrict__ csr_src, float* __restrict__ csr_ea) {
  int e = blockIdx.x * blockDim.x + threadIdx.x;
  if (e < N_EDGES) {
    int d = dst[e];
    int pos = offs[d] + atomicAdd(&cursor[d], 1);
    csr_src[pos] = src[e];
    float4* o4 = reinterpret_cast<float4*>(csr_ea + (size_t)pos * 16);
    const float4* s4 = reinterpret_cast<const float4*>(edge_attr + (size_t)e * 16);
    o4[0] = s4[0]; o4[1] = s4[1]; o4[2] = s4[2]; o4[3] = s4[3];
  }
}

// ---------------------------------------------------------------------------
// fp16 K/V gather helper: load 4*NV halfs -> NV float4
// ---------------------------------------------------------------------------
template <int NV>
__device__ inline void load_kv(const __half* p, float4 (&dst)[NV]) {
  if (NV == 1) {
    float2 r = *reinterpret_cast<const float2*>(p);
    const __half2* h = reinterpret_cast<const __half2*>(&r);
    float2 a = __half22float2(h[0]), b = __half22float2(h[1]);
    dst[0] = make_float4(a.x, a.y, b.x, b.y);
  } else {
    float4 r = *reinterpret_cast<const float4*>(p);
    const __half2* h = reinterpret_cast<const __half2*>(&r);
    float2 a = __half22float2(h[0]), b = __half22float2(h[1]);
    float2 c = __half22float2(h[2]), d = __half22float2(h[3]);
    dst[0] = make_float4(a.x, a.y, b.x, b.y);
    dst[NV - 1] = make_float4(c.x, c.y, d.x, d.y);  // NV==2
  }
}

// ---------------------------------------------------------------------------
// Fused edge kernel (head-local lanes, folded edge-feature algebra, fp16 KV).
// alpha[e,h] = SCALE*(q[dst,h]·k[src,h]) + ea[e]·G[dst,h]  (G inline, q f32)
// agg[h]    = sum attn·v[src,h]  +  (sum attn·ea) @ we[:,h,:]
// Lane l: head h=l>>4, channels c0 = (l&15)*4*NV.
// ---------------------------------------------------------------------------
template <int DOUT>
__global__ __launch_bounds__(256) void edge_attn(
    const float* __restrict__ QS, const __half* __restrict__ KV,
    const float* __restrict__ we, const int* __restrict__ csr_src,
    const float* __restrict__ csr_ea, const int* __restrict__ offs,
    float* __restrict__ out) {
  constexpr int HD = 4 * DOUT;
  constexpr int QSS = HD + DOUT;
  constexpr int KVS = 2 * HD;
  constexpr int NV = DOUT / 64;
  const float SCALE = (DOUT == 64) ? 0.125f : 0.08838834764831845f;

  const int lane = threadIdx.x & 63;
  const int h = lane >> 4, t16 = lane & 15;
  const int n = blockIdx.x * 4 + (threadIdx.x >> 6);  // N_NODES % 4 == 0
  const int c0 = t16 * 4 * NV;

  const float* base = QS + (size_t)n * QSS;
  float4 q[NV], acc[NV];
#pragma unroll
  for (int v = 0; v < NV; ++v) {
    float4 qq = *reinterpret_cast<const float4*>(base + h * DOUT + c0 + 4 * v);
    qq.x *= SCALE; qq.y *= SCALE; qq.z *= SCALE; qq.w *= SCALE;
    q[v] = qq;
    acc[v] = make_float4(0.f, 0.f, 0.f, 0.f);
  }

  // inline G: g = SCALE * sum_c q[h,c]·we[d, h*DOUT+c], kept by lane t16==d
  float g = 0.f;
#pragma unroll
  for (int d = 0; d < 16; ++d) {
    float p = 0.f;
    const float* wb = we + d * HD + h * DOUT + c0;
#pragma unroll
    for (int v = 0; v < NV; ++v) {
      float4 w4 = *reinterpret_cast<const float4*>(wb + 4 * v);
      p += q[v].x * w4.x + q[v].y * w4.y + q[v].z * w4.z + q[v].w * w4.w;
    }
    p += __shfl_xor(p, 1);
    p += __shfl_xor(p, 2);
    p += __shfl_xor(p, 4);
    p += __shfl_xor(p, 8);
    if (t16 == d) g = p;
  }

  float m = -1e30f, lsum = 0.f, tacc = 0.f;

  const int s0 = offs[n], s1 = offs[n + 1];
  int ii = s0;

  for (; ii + 4 <= s1; ii += 4) {
    int sj[4];
#pragma unroll
    for (int j = 0; j < 4; ++j) sj[j] = csr_src[ii + j];
    float ea[4];
#pragma unroll
    for (int j = 0; j < 4; ++j) ea[j] = csr_ea[(size_t)(ii + j) * 16 + t16];
    float4 kj[4][NV], vj[4][NV];
#pragma unroll
    for (int j = 0; j < 4; ++j) {
      const __half* rb = KV + (size_t)sj[j] * KVS + h * DOUT + c0;
      load_kv<NV>(rb, kj[j]);
      load_kv<NV>(rb + HD, vj[j]);
    }
    float a[4];
#pragma unroll
    for (int j = 0; j < 4; ++j) {
      float p = ea[j] * g;
#pragma unroll
      for (int v = 0; v < NV; ++v)
        p += q[v].x * kj[j][v].x + q[v].y * kj[j][v].y + q[v].z * kj[j][v].z +
             q[v].w * kj[j][v].w;
      a[j] = p;
    }
#pragma unroll
    for (int j = 0; j < 4; ++j) {
      a[j] += __shfl_xor(a[j], 1);
      a[j] += __shfl_xor(a[j], 2);
      a[j] += __shfl_xor(a[j], 4);
      a[j] += __shfl_xor(a[j], 8);
    }
    float mn = fmaxf(fmaxf(fmaxf(a[0], a[1]), fmaxf(a[2], a[3])), m);
    float fac = __expf(m - mn);
    float p0 = __expf(a[0] - mn), p1 = __expf(a[1] - mn);
    float p2 = __expf(a[2] - mn), p3 = __expf(a[3] - mn);
    m = mn;
    lsum = lsum * fac + (p0 + p1 + p2 + p3);
    tacc = tacc * fac + p0 * ea[0] + p1 * ea[1] + p2 * ea[2] + p3 * ea[3];
#pragma unroll
    for (int v = 0; v < NV; ++v) {
      float4 av = acc[v];
      av.x = av.x * fac + p0 * vj[0][v].x + p1 * vj[1][v].x + p2 * vj[2][v].x + p3 * vj[3][v].x;
      av.y = av.y * fac + p0 * vj[0][v].y + p1 * vj[1][v].y + p2 * vj[2][v].y + p3 * vj[3][v].y;
      av.z = av.z * fac + p0 * vj[0][v].z + p1 * vj[1][v].z + p2 * vj[2][v].z + p3 * vj[3][v].z;
      av.w = av.w * fac + p0 * vj[0][v].w + p1 * vj[1][v].w + p2 * vj[2][v].w + p3 * vj[3][v].w;
      acc[v] = av;
    }
  }

  for (; ii < s1; ++ii) {
    int s = csr_src[ii];
    float ea0 = csr_ea[(size_t)ii * 16 + t16];
    const __half* rb = KV + (size_t)s * KVS + h * DOUT + c0;
    float4 kk[NV], vv[NV];
    load_kv<NV>(rb, kk);
    load_kv<NV>(rb + HD, vv);
    float a = ea0 * g;
#pragma unroll
    for (int v = 0; v < NV; ++v)
      a += q[v].x * kk[v].x + q[v].y * kk[v].y + q[v].z * kk[v].z + q[v].w * kk[v].w;
    a += __shfl_xor(a, 1);
    a += __shfl_xor(a, 2);
    a += __shfl_xor(a, 4);
    a += __shfl_xor(a, 8);
    float mn = fmaxf(m, a);
    float fac = __expf(m - mn);
    float p = __expf(a - mn);
    m = mn;
    lsum = lsum * fac + p;
    tacc = tacc * fac + p * ea0;
#pragma unroll
    for (int v = 0; v < NV; ++v) {
      acc[v].x = acc[v].x * fac + p * vv[v].x;
      acc[v].y = acc[v].y * fac + p * vv[v].y;
      acc[v].z = acc[v].z * fac + p * vv[v].z;
      acc[v].w = acc[v].w * fac + p * vv[v].w;
    }
  }

  // epilogue: normalize, add (sum attn·ea)@we, head mean, skip, ELU
  float invl = (lsum > 0.f) ? 1.f / lsum : 0.f;
  float tn = tacc * invl;
  float4 val[NV];
#pragma unroll
  for (int v = 0; v < NV; ++v) {
    val[v].x = acc[v].x * invl; val[v].y = acc[v].y * invl;
    val[v].z = acc[v].z * invl; val[v].w = acc[v].w * invl;
  }
#pragma unroll
  for (int d = 0; d < 16; ++d) {
    float td = __shfl(tn, (lane & 48) | d);
    const float* wb = we + d * HD + h * DOUT + c0;
#pragma unroll
    for (int v = 0; v < NV; ++v) {
      float4 w4 = *reinterpret_cast<const float4*>(wb + 4 * v);
      val[v].x += td * w4.x; val[v].y += td * w4.y;
      val[v].z += td * w4.z; val[v].w += td * w4.w;
    }
  }
  // head mean across the 4 groups
#pragma unroll
  for (int v = 0; v < NV; ++v) {
    val[v].x += __shfl_xor(val[v].x, 16); val[v].x += __shfl_xor(val[v].x, 32);
    val[v].y += __shfl_xor(val[v].y, 16); val[v].y += __shfl_xor(val[v].y, 32);
    val[v].z += __shfl_xor(val[v].z, 16); val[v].z += __shfl_xor(val[v].z, 32);
    val[v].w += __shfl_xor(val[v].w, 16); val[v].w += __shfl_xor(val[v].w, 32);
  }
  if (h == 0) {
#pragma unroll
    for (int v = 0; v < NV; ++v) {
      float4 sk = *reinterpret_cast<const float4*>(base + HD + c0 + 4 * v);
      float4 o;
      o.x = 0.25f * val[v].x + sk.x;
      o.y = 0.25f * val[v].y + sk.y;
      o.z = 0.25f * val[v].z + sk.z;
      o.w = 0.25f * val[v].w + sk.w;
      o.x = (o.x > 0.f) ? o.x : expm1f(o.x);
      o.y = (o.y > 0.f) ? o.y : expm1f(o.y);
      o.z = (o.z > 0.f) ? o.z : expm1f(o.z);
      o.w = (o.w > 0.f) ? o.w : expm1f(o.w);
      *reinterpret_cast<float4*>(out + (size_t)n * DOUT + c0 + 4 * v) = o;
    }
  }
}

// ---------------------------------------------------------------------------
// Global mean pool in ONE launch: batch is sorted, so graph g's nodes are a
// contiguous range found by binary search. 64 blocks, no atomics.
// ---------------------------------------------------------------------------
__device__ inline int lower_bound(const int* b, int n, int v) {
  int lo = 0, hi = n;
  while (lo < hi) {
    int mid = (lo + hi) >> 1;
    if (b[mid] < v) lo = mid + 1; else hi = mid;
  }
  return lo;
}

__global__ __launch_bounds__(256) void pool_all(const float* __restrict__ h,
                                                const int* __restrict__ batch,
                                                float* __restrict__ out) {
  const int g = blockIdx.x;
  const int start = lower_bound(batch, N_NODES, g);
  const int end = lower_bound(batch, N_NODES, g + 1);
  const int c = threadIdx.x & 63, j = threadIdx.x >> 6;
  float s = 0.f;
  for (int n = start + j; n < end; n += 4) s += h[(size_t)n * 64 + c];
  __shared__ float red[4][64];
  red[j][c] = s;
  __syncthreads();
  if (j == 0) {
    float tot = red[0][c] + red[1][c] + red[2][c] + red[3][c];
    out[g * 64 + c] = tot / (float)max(end - start, 1);
  }
}

// ---------------------------------------------------------------------------
extern "C" void kernel_launch(void* const* d_in, const int* in_sizes, int n_in,
                              void* d_out, int out_size, void* d_ws, size_t ws_size,
                              hipStream_t stream) {
  const float* x = (const float*)d_in[0];
  const int* edge_index = (const int*)d_in[1];
  const float* edge_attr = (const float*)d_in[2];
  const int* batch = (const int*)d_in[3];
  const int* srcp = edge_index;
  const int* dstp = edge_index + N_EDGES;

  const bool dict_order = in_sizes[5] > 1024;
  const float *wq[3], *wk[3], *wv[3], *wep[3], *wsk[3], *bq[3], *bk[3], *bv[3], *bs[3];
  for (int L = 0; L < 3; ++L) {
    int b = 4 + L * 9;
    if (dict_order) {
      wq[L] = (const float*)d_in[b + 0];
      wk[L] = (const float*)d_in[b + 1];
      wv[L] = (const float*)d_in[b + 2];
      wep[L] = (const float*)d_in[b + 3];
      wsk[L] = (const float*)d_in[b + 4];
      bq[L] = (const float*)d_in[b + 5];
      bk[L] = (const float*)d_in[b + 6];
      bv[L] = (const float*)d_in[b + 7];
      bs[L] = (const float*)d_in[b + 8];
    } else {
      wq[L] = (const float*)d_in[b + 0];
      bq[L] = (const float*)d_in[b + 1];
      wk[L] = (const float*)d_in[b + 2];
      bk[L] = (const float*)d_in[b + 3];
      wv[L] = (const float*)d_in[b + 4];
      bv[L] = (const float*)d_in[b + 5];
      wep[L] = (const float*)d_in[b + 6];
      wsk[L] = (const float*)d_in[b + 7];
      bs[L] = (const float*)d_in[b + 8];
    }
  }

  // Workspace carve (bytes).
  char* p = (char*)d_ws;
  float* qs = (float*)p;      p += (size_t)N_NODES * 640 * 4;   // Q|S f32 (max layer2)
  __half* kv = (__half*)p;    p += (size_t)N_NODES * 1024 * 2;  // K|V f16 (max layer2)
  float* h1 = (float*)p;      p += (size_t)N_NODES * 64 * 4;
  float* h2 = (float*)p;      p += (size_t)N_NODES * 128 * 4;
  float* W1 = (float*)p;      p += 128 * 832 * 4;
  float* b1 = (float*)p;      p += 832 * 4;
  float* W2 = (float*)p;      p += 64 * 1664 * 4;
  float* b2 = (float*)p;      p += 1664 * 4;
  float* W3 = (float*)p;      p += 128 * 832 * 4;
  float* b3 = (float*)p;      p += 832 * 4;
  float* csr_ea = (float*)p;  p += (size_t)N_EDGES * 16 * 4;
  int* cnt = (int*)p;         p += N_NODES * 4;
  int* cursor = (int*)p;      p += N_NODES * 4;
  int* offs = (int*)p;        p += (N_NODES + 1) * 4;
  int* csr_src = (int*)p;     p += N_EDGES * 4;

  // ---- pack all weights (1 launch) ----
  pack_all<<<316, 256, 0, stream>>>(
      wq[0], wk[0], wv[0], wsk[0], bq[0], bk[0], bv[0], bs[0],
      wq[1], wk[1], wv[1], wsk[1], bq[1], bk[1], bv[1], bs[1],
      wq[2], wk[2], wv[2], wsk[2], bq[2], bk[2], bv[2], bs[2],
      W1, b1, W2, b2, W3, b3);

  // ---- CSR build over dst ----
  zero_ints<<<79, 256, 0, stream>>>(cnt, 2 * N_NODES);  // cnt + cursor (adjacent)
  count_dst<<<(N_EDGES + 255) / 256, 256, 0, stream>>>(dstp, cnt);
  scan_offs<<<1, 256, 0, stream>>>(cnt, offs);
  scatter_csr<<<(N_EDGES + 255) / 256, 256, 0, stream>>>(srcp, dstp, edge_attr,
                                                         offs, cursor, csr_src, csr_ea);

  // ---- layer 1: K=128, HD=256, DOUT=64 ----
  {
    dim3 gg(832 / 64, (N_NODES + 63) / 64);
    gemm_bias<128, 256, 64><<<gg, 256, 0, stream>>>(x, W1, b1, qs, kv, N_NODES);
    edge_attn<64><<<N_NODES / 4, 256, 0, stream>>>(qs, kv, wep[0], csr_src,
                                                   csr_ea, offs, h1);
  }
  // ---- layer 2: K=64, HD=512, DOUT=128 ----
  {
    dim3 gg(1664 / 64, (N_NODES + 63) / 64);
    gemm_bias<64, 512, 128><<<gg, 256, 0, stream>>>(h1, W2, b2, qs, kv, N_NODES);
    edge_attn<128><<<N_NODES / 4, 256, 0, stream>>>(qs, kv, wep[1], csr_src,
                                                    csr_ea, offs, h2);
  }
  // ---- layer 3: K=128, HD=256, DOUT=64 ----
  {
    dim3 gg(832 / 64, (N_NODES + 63) / 64);
    gemm_bias<128, 256, 64><<<gg, 256, 0, stream>>>(h2, W3, b3, qs, kv, N_NODES);
    edge_attn<64><<<N_NODES / 4, 256, 0, stream>>>(qs, kv, wep[2], csr_src,
                                                   csr_ea, offs, h1);
  }

  // ---- global mean pool (1 launch) ----
  pool_all<<<N_GRAPHS, 256, 0, stream>>>(h1, batch, (float*)d_out);
}

// Round 5
// 369.982 us; speedup vs baseline: 2.2645x; 1.2207x over previous
//
#include <hip/hip_runtime.h>
#include <hip/hip_fp16.h>
#include <math.h>

#define N_NODES 10000
#define N_EDGES 160000
#define N_GRAPHS 64

using half8 = __attribute__((ext_vector_type(8))) _Float16;
using floatx4 = __attribute__((ext_vector_type(4))) float;

// ---------------------------------------------------------------------------
// MFMA GEMM: [Q|K|V|S] = A[M,K]_f16 @ W[K,W]_f16 + bias_f32. No LDS:
// A frags are 16B row-major loads; W is pre-packed in B-fragment order.
// Block 256 = 4 waves; block tile 64(M)x64(N); wave tile 16(M)x64(N).
// Output split: cols [0,HD)->QS f32, [HD,3HD)->KV f16, [3HD,W)->QS f32.
// ---------------------------------------------------------------------------
template <int K, int HD, int DOUT>
__global__ __launch_bounds__(256) void gemm_mfma(
    const __half* __restrict__ A, const __half* __restrict__ Wp,
    const float* __restrict__ bias, float* __restrict__ QS,
    __half* __restrict__ KV, int M) {
  constexpr int QSS = HD + DOUT;
  constexpr int KS = K / 32;
  const int tid = threadIdx.x;
  const int wave = tid >> 6, lane = tid & 63;
  const int quad = lane >> 4, n16 = lane & 15;
  const int row0 = blockIdx.y * 64 + wave * 16;
  const int col0 = blockIdx.x * 64;
  const int nblk0 = blockIdx.x * 4;

  // A fragments: A[m=lane&15][k=quad*8+j]  (16B contiguous per lane)
  const int arow = min(row0 + n16, M - 1);
  half8 afrag[KS];
#pragma unroll
  for (int s = 0; s < KS; ++s)
    afrag[s] = *reinterpret_cast<const half8*>(A + (size_t)arow * K + s * 32 + quad * 8);

  floatx4 acc[4];
#pragma unroll
  for (int t = 0; t < 4; ++t) {
    acc[t] = (floatx4){0.f, 0.f, 0.f, 0.f};
#pragma unroll
    for (int s = 0; s < KS; ++s) {
      half8 bf = *reinterpret_cast<const half8*>(
          Wp + (((size_t)(nblk0 + t) * KS + s) * 64 + lane) * 8);
      acc[t] = __builtin_amdgcn_mfma_f32_16x16x32_f16(afrag[s], bf, acc[t], 0, 0, 0);
    }
  }

  // epilogue: D[row=quad*4+r][col=lane&15]
#pragma unroll
  for (int t = 0; t < 4; ++t) {
    const int c = col0 + t * 16 + n16;
    const float bv = bias[c];
#pragma unroll
    for (int r = 0; r < 4; ++r) {
      int row = row0 + quad * 4 + r;
      if (row < M) {
        float val = acc[t][r] + bv;
        if (c < HD)
          QS[(size_t)row * QSS + c] = val;
        else if (c < 3 * HD)
          KV[(size_t)row * (2 * HD) + (c - HD)] = __float2half(val);
        else
          QS[(size_t)row * QSS + HD + (c - 3 * HD)] = val;
      }
    }
  }
}

// ---------------------------------------------------------------------------
// Pack all 3 layers' weights into MFMA B-fragment order (f16) + f32 biases.
// Frag index: Wp[((nblk*KS + s)*64 + quad*16 + n)*8 + j] = W[s*32+quad*8+j][nblk*16+n]
// ---------------------------------------------------------------------------
__device__ inline void pack_layer(int i, int K, int HD, int DOUT,
                                  const float* wq, const float* wk,
                                  const float* wv, const float* wsk,
                                  const float* bq, const float* bk,
                                  const float* bv, const float* bs,
                                  __half* Wp, float* bcat) {
  const int W = 3 * HD + DOUT;
  const int KS = K / 32;
  if (i < K * W) {
    int j = i & 7, lane = (i >> 3) & 63, fs = i >> 9;
    int nblk = fs / KS, s = fs - nblk * KS;
    int quad = lane >> 4, n = lane & 15;
    int k = s * 32 + quad * 8 + j, c = nblk * 16 + n;
    float v;
    if (c < HD)           v = wq[k * HD + c];
    else if (c < 2 * HD)  v = wk[k * HD + (c - HD)];
    else if (c < 3 * HD)  v = wv[k * HD + (c - 2 * HD)];
    else                  v = wsk[k * DOUT + (c - 3 * HD)];
    Wp[i] = __float2half(v);
  } else {
    int c = i - K * W;
    float v;
    if (c < HD)           v = bq[c];
    else if (c < 2 * HD)  v = bk[c - HD];
    else if (c < 3 * HD)  v = bv[c - 2 * HD];
    else                  v = bs[c - 3 * HD];
    bcat[c] = v;
  }
}

#define T1 107328   // 128*832 + 832
#define T2 215488   // T1 + 64*1664 + 1664
#define T3 322816   // T2 + 128*832 + 832

__global__ void pack_all(
    const float* wq1, const float* wk1, const float* wv1, const float* ws1,
    const float* bq1, const float* bk1, const float* bv1, const float* bs1,
    const float* wq2, const float* wk2, const float* wv2, const float* ws2,
    const float* bq2, const float* bk2, const float* bv2, const float* bs2,
    const float* wq3, const float* wk3, const float* wv3, const float* ws3,
    const float* bq3, const float* bk3, const float* bv3, const float* bs3,
    __half* W1, float* b1, __half* W2, float* b2, __half* W3, float* b3) {
  for (int i = blockIdx.x * blockDim.x + threadIdx.x; i < T3;
       i += gridDim.x * blockDim.x) {
    if (i < T1)
      pack_layer(i, 128, 256, 64, wq1, wk1, wv1, ws1, bq1, bk1, bv1, bs1, W1, b1);
    else if (i < T2)
      pack_layer(i - T1, 64, 512, 128, wq2, wk2, wv2, ws2, bq2, bk2, bv2, bs2, W2, b2);
    else
      pack_layer(i - T2, 128, 256, 64, wq3, wk3, wv3, ws3, bq3, bk3, bv3, bs3, W3, b3);
  }
}

// ---------------------------------------------------------------------------
// f32 -> f16 convert (for layer-1 A = x)
// ---------------------------------------------------------------------------
__global__ void conv_f16(const float* __restrict__ in, __half* __restrict__ out,
                         int n4) {
  int i = blockIdx.x * blockDim.x + threadIdx.x;
  if (i < n4) {
    float4 v = reinterpret_cast<const float4*>(in)[i];
    __half2* o = reinterpret_cast<__half2*>(out) + 2 * i;
    o[0] = __floats2half2_rn(v.x, v.y);
    o[1] = __floats2half2_rn(v.z, v.w);
  }
}

// ---------------------------------------------------------------------------
// CSR build over dst (+ permute src and edge_attr into CSR order)
// ---------------------------------------------------------------------------
__global__ void zero_ints(int* __restrict__ a, int n) {
  for (int i = blockIdx.x * blockDim.x + threadIdx.x; i < n;
       i += gridDim.x * blockDim.x) a[i] = 0;
}

__global__ void count_dst(const int* __restrict__ dst, int* __restrict__ cnt) {
  int e = blockIdx.x * blockDim.x + threadIdx.x;
  if (e < N_EDGES) atomicAdd(&cnt[dst[e]], 1);
}

__global__ __launch_bounds__(256) void scan_offs(const int* __restrict__ cnt,
                                                 int* __restrict__ offs) {
  __shared__ int part[256];
  const int t = threadIdx.x;
  const int chunk = (N_NODES + 255) / 256;
  const int b = t * chunk;
  const int e = min(N_NODES, b + chunk);
  int s = 0;
  for (int i = b; i < e; ++i) s += cnt[i];
  part[t] = s;
  __syncthreads();
  for (int off = 1; off < 256; off <<= 1) {
    int v = (t >= off) ? part[t - off] : 0;
    __syncthreads();
    part[t] += v;
    __syncthreads();
  }
  int pre = (t == 0) ? 0 : part[t - 1];
  for (int i = b; i < e; ++i) { offs[i] = pre; pre += cnt[i]; }
  if (t == 0) offs[N_NODES] = part[255];
}

__global__ void scatter_csr(const int* __restrict__ src, const int* __restrict__ dst,
                            const float* __restrict__ edge_attr,
                            const int* __restrict__ offs, int* __restrict__ cursor,
                            int* __restrict__ csr_src, float* __restrict__ csr_ea) {
  int e = blockIdx.x * blockDim.x + threadIdx.x;
  if (e < N_EDGES) {
    int d = dst[e];
    int pos = offs[d] + atomicAdd(&cursor[d], 1);
    csr_src[pos] = src[e];
    float4* o4 = reinterpret_cast<float4*>(csr_ea + (size_t)pos * 16);
    const float4* s4 = reinterpret_cast<const float4*>(edge_attr + (size_t)e * 16);
    o4[0] = s4[0]; o4[1] = s4[1]; o4[2] = s4[2]; o4[3] = s4[3];
  }
}

// ---------------------------------------------------------------------------
// fp16 K/V gather helper: load 4*NV halfs -> NV float4
// ---------------------------------------------------------------------------
template <int NV>
__device__ inline void load_kv(const __half* p, float4 (&dst)[NV]) {
  if (NV == 1) {
    float2 r = *reinterpret_cast<const float2*>(p);
    const __half2* h = reinterpret_cast<const __half2*>(&r);
    float2 a = __half22float2(h[0]), b = __half22float2(h[1]);
    dst[0] = make_float4(a.x, a.y, b.x, b.y);
  } else {
    float4 r = *reinterpret_cast<const float4*>(p);
    const __half2* h = reinterpret_cast<const __half2*>(&r);
    float2 a = __half22float2(h[0]), b = __half22float2(h[1]);
    float2 c = __half22float2(h[2]), d = __half22float2(h[3]);
    dst[0] = make_float4(a.x, a.y, b.x, b.y);
    dst[NV - 1] = make_float4(c.x, c.y, d.x, d.y);  // NV==2
  }
}

// ---------------------------------------------------------------------------
// Fused edge kernel (head-local lanes, folded edge-feature algebra, fp16 KV).
// Writes f32 output (for pool / reference) AND f16 output (next layer's A).
// ---------------------------------------------------------------------------
template <int DOUT>
__global__ __launch_bounds__(256) void edge_attn(
    const float* __restrict__ QS, const __half* __restrict__ KV,
    const float* __restrict__ we, const int* __restrict__ csr_src,
    const float* __restrict__ csr_ea, const int* __restrict__ offs,
    float* __restrict__ out, __half* __restrict__ out16) {
  constexpr int HD = 4 * DOUT;
  constexpr int QSS = HD + DOUT;
  constexpr int KVS = 2 * HD;
  constexpr int NV = DOUT / 64;
  const float SCALE = (DOUT == 64) ? 0.125f : 0.08838834764831845f;

  const int lane = threadIdx.x & 63;
  const int h = lane >> 4, t16 = lane & 15;
  const int n = blockIdx.x * 4 + (threadIdx.x >> 6);  // N_NODES % 4 == 0
  const int c0 = t16 * 4 * NV;

  const float* base = QS + (size_t)n * QSS;
  float4 q[NV], acc[NV];
#pragma unroll
  for (int v = 0; v < NV; ++v) {
    float4 qq = *reinterpret_cast<const float4*>(base + h * DOUT + c0 + 4 * v);
    qq.x *= SCALE; qq.y *= SCALE; qq.z *= SCALE; qq.w *= SCALE;
    q[v] = qq;
    acc[v] = make_float4(0.f, 0.f, 0.f, 0.f);
  }

  // inline G: g = SCALE * sum_c q[h,c]·we[d, h*DOUT+c], kept by lane t16==d
  float g = 0.f;
#pragma unroll
  for (int d = 0; d < 16; ++d) {
    float p = 0.f;
    const float* wb = we + d * HD + h * DOUT + c0;
#pragma unroll
    for (int v = 0; v < NV; ++v) {
      float4 w4 = *reinterpret_cast<const float4*>(wb + 4 * v);
      p += q[v].x * w4.x + q[v].y * w4.y + q[v].z * w4.z + q[v].w * w4.w;
    }
    p += __shfl_xor(p, 1);
    p += __shfl_xor(p, 2);
    p += __shfl_xor(p, 4);
    p += __shfl_xor(p, 8);
    if (t16 == d) g = p;
  }

  float m = -1e30f, lsum = 0.f, tacc = 0.f;

  const int s0 = offs[n], s1 = offs[n + 1];
  int ii = s0;

  for (; ii + 4 <= s1; ii += 4) {
    int sj[4];
#pragma unroll
    for (int j = 0; j < 4; ++j) sj[j] = csr_src[ii + j];
    float ea[4];
#pragma unroll
    for (int j = 0; j < 4; ++j) ea[j] = csr_ea[(size_t)(ii + j) * 16 + t16];
    float4 kj[4][NV], vj[4][NV];
#pragma unroll
    for (int j = 0; j < 4; ++j) {
      const __half* rb = KV + (size_t)sj[j] * KVS + h * DOUT + c0;
      load_kv<NV>(rb, kj[j]);
      load_kv<NV>(rb + HD, vj[j]);
    }
    float a[4];
#pragma unroll
    for (int j = 0; j < 4; ++j) {
      float p = ea[j] * g;
#pragma unroll
      for (int v = 0; v < NV; ++v)
        p += q[v].x * kj[j][v].x + q[v].y * kj[j][v].y + q[v].z * kj[j][v].z +
             q[v].w * kj[j][v].w;
      a[j] = p;
    }
#pragma unroll
    for (int j = 0; j < 4; ++j) {
      a[j] += __shfl_xor(a[j], 1);
      a[j] += __shfl_xor(a[j], 2);
      a[j] += __shfl_xor(a[j], 4);
      a[j] += __shfl_xor(a[j], 8);
    }
    float mn = fmaxf(fmaxf(fmaxf(a[0], a[1]), fmaxf(a[2], a[3])), m);
    float fac = __expf(m - mn);
    float p0 = __expf(a[0] - mn), p1 = __expf(a[1] - mn);
    float p2 = __expf(a[2] - mn), p3 = __expf(a[3] - mn);
    m = mn;
    lsum = lsum * fac + (p0 + p1 + p2 + p3);
    tacc = tacc * fac + p0 * ea[0] + p1 * ea[1] + p2 * ea[2] + p3 * ea[3];
#pragma unroll
    for (int v = 0; v < NV; ++v) {
      float4 av = acc[v];
      av.x = av.x * fac + p0 * vj[0][v].x + p1 * vj[1][v].x + p2 * vj[2][v].x + p3 * vj[3][v].x;
      av.y = av.y * fac + p0 * vj[0][v].y + p1 * vj[1][v].y + p2 * vj[2][v].y + p3 * vj[3][v].y;
      av.z = av.z * fac + p0 * vj[0][v].z + p1 * vj[1][v].z + p2 * vj[2][v].z + p3 * vj[3][v].z;
      av.w = av.w * fac + p0 * vj[0][v].w + p1 * vj[1][v].w + p2 * vj[2][v].w + p3 * vj[3][v].w;
      acc[v] = av;
    }
  }

  for (; ii < s1; ++ii) {
    int s = csr_src[ii];
    float ea0 = csr_ea[(size_t)ii * 16 + t16];
    const __half* rb = KV + (size_t)s * KVS + h * DOUT + c0;
    float4 kk[NV], vv[NV];
    load_kv<NV>(rb, kk);
    load_kv<NV>(rb + HD, vv);
    float a = ea0 * g;
#pragma unroll
    for (int v = 0; v < NV; ++v)
      a += q[v].x * kk[v].x + q[v].y * kk[v].y + q[v].z * kk[v].z + q[v].w * kk[v].w;
    a += __shfl_xor(a, 1);
    a += __shfl_xor(a, 2);
    a += __shfl_xor(a, 4);
    a += __shfl_xor(a, 8);
    float mn = fmaxf(m, a);
    float fac = __expf(m - mn);
    float p = __expf(a - mn);
    m = mn;
    lsum = lsum * fac + p;
    tacc = tacc * fac + p * ea0;
#pragma unroll
    for (int v = 0; v < NV; ++v) {
      acc[v].x = acc[v].x * fac + p * vv[v].x;
      acc[v].y = acc[v].y * fac + p * vv[v].y;
      acc[v].z = acc[v].z * fac + p * vv[v].z;
      acc[v].w = acc[v].w * fac + p * vv[v].w;
    }
  }

  // epilogue: normalize, add (sum attn·ea)@we, head mean, skip, ELU
  float invl = (lsum > 0.f) ? 1.f / lsum : 0.f;
  float tn = tacc * invl;
  float4 val[NV];
#pragma unroll
  for (int v = 0; v < NV; ++v) {
    val[v].x = acc[v].x * invl; val[v].y = acc[v].y * invl;
    val[v].z = acc[v].z * invl; val[v].w = acc[v].w * invl;
  }
#pragma unroll
  for (int d = 0; d < 16; ++d) {
    float td = __shfl(tn, (lane & 48) | d);
    const float* wb = we + d * HD + h * DOUT + c0;
#pragma unroll
    for (int v = 0; v < NV; ++v) {
      float4 w4 = *reinterpret_cast<const float4*>(wb + 4 * v);
      val[v].x += td * w4.x; val[v].y += td * w4.y;
      val[v].z += td * w4.z; val[v].w += td * w4.w;
    }
  }
  // head mean across the 4 groups
#pragma unroll
  for (int v = 0; v < NV; ++v) {
    val[v].x += __shfl_xor(val[v].x, 16); val[v].x += __shfl_xor(val[v].x, 32);
    val[v].y += __shfl_xor(val[v].y, 16); val[v].y += __shfl_xor(val[v].y, 32);
    val[v].z += __shfl_xor(val[v].z, 16); val[v].z += __shfl_xor(val[v].z, 32);
    val[v].w += __shfl_xor(val[v].w, 16); val[v].w += __shfl_xor(val[v].w, 32);
  }
  if (h == 0) {
#pragma unroll
    for (int v = 0; v < NV; ++v) {
      float4 sk = *reinterpret_cast<const float4*>(base + HD + c0 + 4 * v);
      float4 o;
      o.x = 0.25f * val[v].x + sk.x;
      o.y = 0.25f * val[v].y + sk.y;
      o.z = 0.25f * val[v].z + sk.z;
      o.w = 0.25f * val[v].w + sk.w;
      o.x = (o.x > 0.f) ? o.x : expm1f(o.x);
      o.y = (o.y > 0.f) ? o.y : expm1f(o.y);
      o.z = (o.z > 0.f) ? o.z : expm1f(o.z);
      o.w = (o.w > 0.f) ? o.w : expm1f(o.w);
      *reinterpret_cast<float4*>(out + (size_t)n * DOUT + c0 + 4 * v) = o;
      __half2* o16 = reinterpret_cast<__half2*>(out16 + (size_t)n * DOUT + c0 + 4 * v);
      o16[0] = __floats2half2_rn(o.x, o.y);
      o16[1] = __floats2half2_rn(o.z, o.w);
    }
  }
}

// ---------------------------------------------------------------------------
// Global mean pool in ONE launch (batch sorted -> contiguous ranges).
// ---------------------------------------------------------------------------
__device__ inline int lower_bound(const int* b, int n, int v) {
  int lo = 0, hi = n;
  while (lo < hi) {
    int mid = (lo + hi) >> 1;
    if (b[mid] < v) lo = mid + 1; else hi = mid;
  }
  return lo;
}

__global__ __launch_bounds__(256) void pool_all(const float* __restrict__ h,
                                                const int* __restrict__ batch,
                                                float* __restrict__ out) {
  const int g = blockIdx.x;
  const int start = lower_bound(batch, N_NODES, g);
  const int end = lower_bound(batch, N_NODES, g + 1);
  const int c = threadIdx.x & 63, j = threadIdx.x >> 6;
  float s = 0.f;
  for (int n = start + j; n < end; n += 4) s += h[(size_t)n * 64 + c];
  __shared__ float red[4][64];
  red[j][c] = s;
  __syncthreads();
  if (j == 0) {
    float tot = red[0][c] + red[1][c] + red[2][c] + red[3][c];
    out[g * 64 + c] = tot / (float)max(end - start, 1);
  }
}

// ---------------------------------------------------------------------------
extern "C" void kernel_launch(void* const* d_in, const int* in_sizes, int n_in,
                              void* d_out, int out_size, void* d_ws, size_t ws_size,
                              hipStream_t stream) {
  const float* x = (const float*)d_in[0];
  const int* edge_index = (const int*)d_in[1];
  const float* edge_attr = (const float*)d_in[2];
  const int* batch = (const int*)d_in[3];
  const int* srcp = edge_index;
  const int* dstp = edge_index + N_EDGES;

  const bool dict_order = in_sizes[5] > 1024;
  const float *wq[3], *wk[3], *wv[3], *wep[3], *wsk[3], *bq[3], *bk[3], *bv[3], *bs[3];
  for (int L = 0; L < 3; ++L) {
    int b = 4 + L * 9;
    if (dict_order) {
      wq[L] = (const float*)d_in[b + 0];
      wk[L] = (const float*)d_in[b + 1];
      wv[L] = (const float*)d_in[b + 2];
      wep[L] = (const float*)d_in[b + 3];
      wsk[L] = (const float*)d_in[b + 4];
      bq[L] = (const float*)d_in[b + 5];
      bk[L] = (const float*)d_in[b + 6];
      bv[L] = (const float*)d_in[b + 7];
      bs[L] = (const float*)d_in[b + 8];
    } else {
      wq[L] = (const float*)d_in[b + 0];
      bq[L] = (const float*)d_in[b + 1];
      wk[L] = (const float*)d_in[b + 2];
      bk[L] = (const float*)d_in[b + 3];
      wv[L] = (const float*)d_in[b + 4];
      bv[L] = (const float*)d_in[b + 5];
      wep[L] = (const float*)d_in[b + 6];
      wsk[L] = (const float*)d_in[b + 7];
      bs[L] = (const float*)d_in[b + 8];
    }
  }

  // Workspace carve (bytes).
  char* p = (char*)d_ws;
  float* qs = (float*)p;      p += (size_t)N_NODES * 640 * 4;   // Q|S f32 (max L2)
  __half* kv = (__half*)p;    p += (size_t)N_NODES * 1024 * 2;  // K|V f16 (max L2)
  float* h1 = (float*)p;      p += (size_t)N_NODES * 64 * 4;
  float* h2 = (float*)p;      p += (size_t)N_NODES * 128 * 4;
  __half* x16 = (__half*)p;   p += (size_t)N_NODES * 128 * 2;
  __half* h16 = (__half*)p;   p += (size_t)N_NODES * 128 * 2;
  __half* W1 = (__half*)p;    p += 128 * 832 * 2;
  __half* W2 = (__half*)p;    p += 64 * 1664 * 2;
  __half* W3 = (__half*)p;    p += 128 * 832 * 2;
  float* b1 = (float*)p;      p += 832 * 4;
  float* b2 = (float*)p;      p += 1664 * 4;
  float* b3 = (float*)p;      p += 832 * 4;
  float* csr_ea = (float*)p;  p += (size_t)N_EDGES * 16 * 4;
  int* cnt = (int*)p;         p += N_NODES * 4;
  int* cursor = (int*)p;      p += N_NODES * 4;
  int* offs = (int*)p;        p += (N_NODES + 1) * 4;
  int* csr_src = (int*)p;     p += N_EDGES * 4;

  // ---- pack weights (f16 fragment order) + convert x ----
  pack_all<<<632, 256, 0, stream>>>(
      wq[0], wk[0], wv[0], wsk[0], bq[0], bk[0], bv[0], bs[0],
      wq[1], wk[1], wv[1], wsk[1], bq[1], bk[1], bv[1], bs[1],
      wq[2], wk[2], wv[2], wsk[2], bq[2], bk[2], bv[2], bs[2],
      W1, b1, W2, b2, W3, b3);
  conv_f16<<<(N_NODES * 128 / 4 + 255) / 256, 256, 0, stream>>>(x, x16,
                                                                N_NODES * 128 / 4);

  // ---- CSR build over dst ----
  zero_ints<<<79, 256, 0, stream>>>(cnt, 2 * N_NODES);  // cnt + cursor (adjacent)
  count_dst<<<(N_EDGES + 255) / 256, 256, 0, stream>>>(dstp, cnt);
  scan_offs<<<1, 256, 0, stream>>>(cnt, offs);
  scatter_csr<<<(N_EDGES + 255) / 256, 256, 0, stream>>>(srcp, dstp, edge_attr,
                                                         offs, cursor, csr_src, csr_ea);

  const int MT = (N_NODES + 63) / 64;
  // ---- layer 1: K=128, HD=256, DOUT=64 ----
  gemm_mfma<128, 256, 64><<<dim3(832 / 64, MT), 256, 0, stream>>>(x16, W1, b1, qs,
                                                                  kv, N_NODES);
  edge_attn<64><<<N_NODES / 4, 256, 0, stream>>>(qs, kv, wep[0], csr_src, csr_ea,
                                                 offs, h1, h16);
  // ---- layer 2: K=64, HD=512, DOUT=128 ----
  gemm_mfma<64, 512, 128><<<dim3(1664 / 64, MT), 256, 0, stream>>>(h16, W2, b2, qs,
                                                                   kv, N_NODES);
  edge_attn<128><<<N_NODES / 4, 256, 0, stream>>>(qs, kv, wep[1], csr_src, csr_ea,
                                                  offs, h2, h16);
  // ---- layer 3: K=128, HD=256, DOUT=64 ----
  gemm_mfma<128, 256, 64><<<dim3(832 / 64, MT), 256, 0, stream>>>(h16, W3, b3, qs,
                                                                  kv, N_NODES);
  edge_attn<64><<<N_NODES / 4, 256, 0, stream>>>(qs, kv, wep[2], csr_src, csr_ea,
                                                 offs, h1, x16 /*dummy f16 out*/);

  // ---- global mean pool ----
  pool_all<<<N_GRAPHS, 256, 0, stream>>>(h1, batch, (float*)d_out);
}

// Round 6
// 353.992 us; speedup vs baseline: 2.3667x; 1.0452x over previous
//
#include <hip/hip_runtime.h>
#include <hip/hip_fp16.h>
#include <math.h>

#define N_NODES 10000
#define N_EDGES 160000
#define N_GRAPHS 64

using half8 = __attribute__((ext_vector_type(8))) _Float16;
using floatx4 = __attribute__((ext_vector_type(4))) float;

// raw f16 fragment word: 4 halfs (NV=1) or 8 halfs (NV=2)
template <int NV> struct KW;
template <> struct KW<1> { using T = uint2; };
template <> struct KW<2> { using T = uint4; };

__device__ inline void cvt_kv(const uint2& w, float4* dst) {
  float2 a = __half22float2(*reinterpret_cast<const __half2*>(&w.x));
  float2 b = __half22float2(*reinterpret_cast<const __half2*>(&w.y));
  dst[0] = make_float4(a.x, a.y, b.x, b.y);
}
__device__ inline void cvt_kv(const uint4& w, float4* dst) {
  float2 a = __half22float2(*reinterpret_cast<const __half2*>(&w.x));
  float2 b = __half22float2(*reinterpret_cast<const __half2*>(&w.y));
  float2 c = __half22float2(*reinterpret_cast<const __half2*>(&w.z));
  float2 d = __half22float2(*reinterpret_cast<const __half2*>(&w.w));
  dst[0] = make_float4(a.x, a.y, b.x, b.y);
  dst[1] = make_float4(c.x, c.y, d.x, d.y);
}

// ---------------------------------------------------------------------------
// MFMA GEMM: [Q|G|K|V|S] = A[M,K]_f16 @ Wp_f16 + bias_f32.  No LDS.
// W' = 3*HD + DOUT + 64.  Output split (all f16):
//   c < HD+64          -> QS[row*QSS + c]            (Q pre-scaled, G cols)
//   c < 3*HD+64        -> KV[row*2HD + (c-HD-64)]
//   else               -> QS[row*QSS + HD+64 + ...]  (S skip)
// ---------------------------------------------------------------------------
template <int K, int HD, int DOUT>
__global__ __launch_bounds__(256) void gemm_mfma(
    const __half* __restrict__ A, const __half* __restrict__ Wp,
    const float* __restrict__ bias, __half* __restrict__ QS,
    __half* __restrict__ KV, int M) {
  constexpr int QSS = HD + 64 + DOUT;
  constexpr int KS = K / 32;
  const int tid = threadIdx.x;
  const int wave = tid >> 6, lane = tid & 63;
  const int quad = lane >> 4, n16 = lane & 15;
  const int row0 = blockIdx.y * 64 + wave * 16;
  const int col0 = blockIdx.x * 64;
  const int nblk0 = blockIdx.x * 4;

  const int arow = min(row0 + n16, M - 1);
  half8 afrag[KS];
#pragma unroll
  for (int s = 0; s < KS; ++s)
    afrag[s] = *reinterpret_cast<const half8*>(A + (size_t)arow * K + s * 32 + quad * 8);

  floatx4 acc[4];
#pragma unroll
  for (int t = 0; t < 4; ++t) {
    acc[t] = (floatx4){0.f, 0.f, 0.f, 0.f};
#pragma unroll
    for (int s = 0; s < KS; ++s) {
      half8 bf = *reinterpret_cast<const half8*>(
          Wp + (((size_t)(nblk0 + t) * KS + s) * 64 + lane) * 8);
      acc[t] = __builtin_amdgcn_mfma_f32_16x16x32_f16(afrag[s], bf, acc[t], 0, 0, 0);
    }
  }

#pragma unroll
  for (int t = 0; t < 4; ++t) {
    const int c = col0 + t * 16 + n16;
    const float bv = bias[c];
#pragma unroll
    for (int r = 0; r < 4; ++r) {
      int row = row0 + quad * 4 + r;
      if (row < M) {
        __half val = __float2half(acc[t][r] + bv);
        if (c < HD + 64)
          QS[(size_t)row * QSS + c] = val;
        else if (c < 3 * HD + 64)
          KV[(size_t)row * (2 * HD) + (c - HD - 64)] = val;
        else
          QS[(size_t)row * QSS + HD + 64 + (c - 3 * HD - 64)] = val;
      }
    }
  }
}

// ---------------------------------------------------------------------------
// Pack weights into B-fragment order (f16), building the fused G columns:
//   Wg[k, h*16+d] = SCALE * sum_c wq[k, h*DOUT+c] * we[d, h*DOUT+c]
// Q columns pre-scaled by SCALE. Also converts x -> f16 (tail range).
// ---------------------------------------------------------------------------
__device__ inline void pack_layer(int i, int K, int HD, int DOUT, float scale,
                                  const float* wq, const float* wk,
                                  const float* wv, const float* wsk,
                                  const float* we, const float* bq,
                                  const float* bk, const float* bv,
                                  const float* bs, __half* Wp, float* bcat) {
  const int W = 3 * HD + DOUT + 64;
  const int KS = K / 32;
  if (i < K * W) {
    int j = i & 7, lane = (i >> 3) & 63, fs = i >> 9;
    int nblk = fs / KS, s = fs - nblk * KS;
    int quad = lane >> 4, n = lane & 15;
    int k = s * 32 + quad * 8 + j, c = nblk * 16 + n;
    float v;
    if (c < HD) {
      v = wq[k * HD + c] * scale;
    } else if (c < HD + 64) {
      int gi = c - HD, hh = gi >> 4, d = gi & 15;
      float a = 0.f;
      for (int cc = 0; cc < DOUT; ++cc)
        a += wq[k * HD + hh * DOUT + cc] * we[d * HD + hh * DOUT + cc];
      v = a * scale;
    } else if (c < 2 * HD + 64) {
      v = wk[k * HD + (c - HD - 64)];
    } else if (c < 3 * HD + 64) {
      v = wv[k * HD + (c - 2 * HD - 64)];
    } else {
      v = wsk[k * DOUT + (c - 3 * HD - 64)];
    }
    Wp[i] = __float2half(v);
  } else {
    int c = i - K * W;
    float v;
    if (c < HD) {
      v = bq[c] * scale;
    } else if (c < HD + 64) {
      int gi = c - HD, hh = gi >> 4, d = gi & 15;
      float a = 0.f;
      for (int cc = 0; cc < DOUT; ++cc)
        a += bq[hh * DOUT + cc] * we[d * HD + hh * DOUT + cc];
      v = a * scale;
    } else if (c < 2 * HD + 64) {
      v = bk[c - HD - 64];
    } else if (c < 3 * HD + 64) {
      v = bv[c - 2 * HD - 64];
    } else {
      v = bs[c - 3 * HD - 64];
    }
    bcat[c] = v;
  }
}

#define T1 115584            // 128*896 + 896
#define T2 227904            // T1 + 64*1728 + 1728
#define T3 343488            // T2 + 128*896 + 896
#define TCONV (N_NODES * 32) // x float4 count
#define TTOT (T3 + TCONV)

__global__ void pack_all(
    const float* wq1, const float* wk1, const float* wv1, const float* ws1,
    const float* we1, const float* bq1, const float* bk1, const float* bv1,
    const float* bs1,
    const float* wq2, const float* wk2, const float* wv2, const float* ws2,
    const float* we2, const float* bq2, const float* bk2, const float* bv2,
    const float* bs2,
    const float* wq3, const float* wk3, const float* wv3, const float* ws3,
    const float* we3, const float* bq3, const float* bk3, const float* bv3,
    const float* bs3,
    __half* W1, float* b1, __half* W2, float* b2, __half* W3, float* b3,
    const float* x, __half* x16) {
  const float SC1 = 0.125f, SC2 = 0.08838834764831845f;
  for (int i = blockIdx.x * blockDim.x + threadIdx.x; i < TTOT;
       i += gridDim.x * blockDim.x) {
    if (i < T1)
      pack_layer(i, 128, 256, 64, SC1, wq1, wk1, wv1, ws1, we1, bq1, bk1, bv1, bs1, W1, b1);
    else if (i < T2)
      pack_layer(i - T1, 64, 512, 128, SC2, wq2, wk2, wv2, ws2, we2, bq2, bk2, bv2, bs2, W2, b2);
    else if (i < T3)
      pack_layer(i - T2, 128, 256, 64, SC1, wq3, wk3, wv3, ws3, we3, bq3, bk3, bv3, bs3, W3, b3);
    else {
      int k = i - T3;
      float4 v = reinterpret_cast<const float4*>(x)[k];
      __half2* o = reinterpret_cast<__half2*>(x16) + 2 * k;
      o[0] = __floats2half2_rn(v.x, v.y);
      o[1] = __floats2half2_rn(v.z, v.w);
    }
  }
}

// ---------------------------------------------------------------------------
// CSR build over dst
// ---------------------------------------------------------------------------
__global__ void count_dst(const int* __restrict__ dst, int* __restrict__ cnt) {
  int e = blockIdx.x * blockDim.x + threadIdx.x;
  if (e < N_EDGES) atomicAdd(&cnt[dst[e]], 1);
}

__global__ __launch_bounds__(256) void scan_offs(const int* __restrict__ cnt,
                                                 int* __restrict__ offs) {
  __shared__ int part[256];
  const int t = threadIdx.x;
  const int chunk = (N_NODES + 255) / 256;
  const int b = t * chunk;
  const int e = min(N_NODES, b + chunk);
  int s = 0;
  for (int i = b; i < e; ++i) s += cnt[i];
  part[t] = s;
  __syncthreads();
  for (int off = 1; off < 256; off <<= 1) {
    int v = (t >= off) ? part[t - off] : 0;
    __syncthreads();
    part[t] += v;
    __syncthreads();
  }
  int pre = (t == 0) ? 0 : part[t - 1];
  for (int i = b; i < e; ++i) { offs[i] = pre; pre += cnt[i]; }
  if (t == 0) offs[N_NODES] = part[255];
}

__global__ void scatter_csr(const int* __restrict__ src, const int* __restrict__ dst,
                            const float* __restrict__ edge_attr,
                            const int* __restrict__ offs, int* __restrict__ cursor,
                            int* __restrict__ csr_src, float* __restrict__ csr_ea) {
  int e = blockIdx.x * blockDim.x + threadIdx.x;
  if (e < N_EDGES) {
    int d = dst[e];
    int pos = offs[d] + atomicAdd(&cursor[d], 1);
    csr_src[pos] = src[e];
    float4* o4 = reinterpret_cast<float4*>(csr_ea + (size_t)pos * 16);
    const float4* s4 = reinterpret_cast<const float4*>(edge_attr + (size_t)e * 16);
    o4[0] = s4[0]; o4[1] = s4[1]; o4[2] = s4[2]; o4[3] = s4[3];
  }
}

// ---------------------------------------------------------------------------
// Fused edge kernel: head-local lanes, folded edge algebra, fp16 QS/KV,
// software-pipelined 4-edge groups (ping-pong raw-f16 buffers), no-max
// softmax (logits bounded; exact math unchanged).
// QS row: [Q(HD, pre-scaled) | G(64, pre-scaled) | S(DOUT)], f16.
// ---------------------------------------------------------------------------
template <int DOUT>
__global__ __launch_bounds__(256) void edge_attn(
    const __half* __restrict__ QS, const __half* __restrict__ KV,
    const float* __restrict__ we, const int* __restrict__ csr_src,
    const float* __restrict__ csr_ea, const int* __restrict__ offs,
    float* __restrict__ out, __half* __restrict__ out16) {
  constexpr int HD = 4 * DOUT;
  constexpr int QSS = HD + 64 + DOUT;
  constexpr int KVS = 2 * HD;
  constexpr int NV = DOUT / 64;
  using KWT = typename KW<NV>::T;

  const int lane = threadIdx.x & 63;
  const int h = lane >> 4, t16 = lane & 15;
  const int n = blockIdx.x * 4 + (threadIdx.x >> 6);  // N_NODES % 4 == 0
  const int c0 = t16 * 4 * NV;

  const __half* base = QS + (size_t)n * QSS;
  float4 q[NV], acc[NV];
  {
    KWT qw = *reinterpret_cast<const KWT*>(base + h * DOUT + c0);
    cvt_kv(qw, q);
  }
#pragma unroll
  for (int v = 0; v < NV; ++v) acc[v] = make_float4(0.f, 0.f, 0.f, 0.f);
  const float g = __half2float(base[HD + h * 16 + t16]);  // pre-scaled G

  float lsum = 0.f, tacc = 0.f;

  const int s0 = offs[n], s1 = offs[n + 1];

  int sjA[4], sjB[4];
  float eaA[4], eaB[4];
  KWT krA[4], vrA[4], krB[4], vrB[4];

  auto load_grp = [&](int bi, int (&sj)[4], float (&ea)[4], KWT (&kr)[4],
                      KWT (&vr)[4]) {
#pragma unroll
    for (int j = 0; j < 4; ++j) sj[j] = csr_src[bi + j];
#pragma unroll
    for (int j = 0; j < 4; ++j) ea[j] = csr_ea[(size_t)(bi + j) * 16 + t16];
#pragma unroll
    for (int j = 0; j < 4; ++j) {
      const __half* rb = KV + (size_t)sj[j] * KVS + h * DOUT + c0;
      kr[j] = *reinterpret_cast<const KWT*>(rb);
      vr[j] = *reinterpret_cast<const KWT*>(rb + HD);
    }
  };

  auto compute_grp = [&](float (&ea)[4], KWT (&kr)[4], KWT (&vr)[4]) {
    float a[4];
#pragma unroll
    for (int j = 0; j < 4; ++j) {
      float4 kk[NV];
      cvt_kv(kr[j], kk);
      float p = ea[j] * g;
#pragma unroll
      for (int v = 0; v < NV; ++v)
        p += q[v].x * kk[v].x + q[v].y * kk[v].y + q[v].z * kk[v].z +
             q[v].w * kk[v].w;
      a[j] = p;
    }
#pragma unroll
    for (int j = 0; j < 4; ++j) {
      a[j] += __shfl_xor(a[j], 1);
      a[j] += __shfl_xor(a[j], 2);
      a[j] += __shfl_xor(a[j], 4);
      a[j] += __shfl_xor(a[j], 8);
    }
    float p0 = __expf(a[0]), p1 = __expf(a[1]);
    float p2 = __expf(a[2]), p3 = __expf(a[3]);
    lsum += p0 + p1 + p2 + p3;
    tacc += p0 * ea[0] + p1 * ea[1] + p2 * ea[2] + p3 * ea[3];
    float pj[4] = {p0, p1, p2, p3};
#pragma unroll
    for (int j = 0; j < 4; ++j) {
      float4 vv[NV];
      cvt_kv(vr[j], vv);
#pragma unroll
      for (int v = 0; v < NV; ++v) {
        acc[v].x += pj[j] * vv[v].x;
        acc[v].y += pj[j] * vv[v].y;
        acc[v].z += pj[j] * vv[v].z;
        acc[v].w += pj[j] * vv[v].w;
      }
    }
  };

  int ii = s0;
  const int end_full = s0 + ((s1 - s0) & ~3);
  if (ii < end_full) {
    load_grp(ii, sjA, eaA, krA, vrA);
    for (;;) {
      if (ii + 4 >= end_full) { compute_grp(eaA, krA, vrA); ii += 4; break; }
      load_grp(ii + 4, sjB, eaB, krB, vrB);
      compute_grp(eaA, krA, vrA);
      ii += 4;
      if (ii + 4 >= end_full) { compute_grp(eaB, krB, vrB); ii += 4; break; }
      load_grp(ii + 4, sjA, eaA, krA, vrA);
      compute_grp(eaB, krB, vrB);
      ii += 4;
    }
  }

  for (; ii < s1; ++ii) {
    int s = csr_src[ii];
    float ea0 = csr_ea[(size_t)ii * 16 + t16];
    const __half* rb = KV + (size_t)s * KVS + h * DOUT + c0;
    KWT kw = *reinterpret_cast<const KWT*>(rb);
    KWT vw = *reinterpret_cast<const KWT*>(rb + HD);
    float4 kk[NV], vv[NV];
    cvt_kv(kw, kk);
    cvt_kv(vw, vv);
    float a = ea0 * g;
#pragma unroll
    for (int v = 0; v < NV; ++v)
      a += q[v].x * kk[v].x + q[v].y * kk[v].y + q[v].z * kk[v].z + q[v].w * kk[v].w;
    a += __shfl_xor(a, 1);
    a += __shfl_xor(a, 2);
    a += __shfl_xor(a, 4);
    a += __shfl_xor(a, 8);
    float p = __expf(a);
    lsum += p;
    tacc += p * ea0;
#pragma unroll
    for (int v = 0; v < NV; ++v) {
      acc[v].x += p * vv[v].x;
      acc[v].y += p * vv[v].y;
      acc[v].z += p * vv[v].z;
      acc[v].w += p * vv[v].w;
    }
  }

  // epilogue: normalize, add (sum attn*ea)@we, head mean, skip, ELU
  float invl = (lsum > 0.f) ? 1.f / lsum : 0.f;
  float tn = tacc * invl;
  float4 val[NV];
#pragma unroll
  for (int v = 0; v < NV; ++v) {
    val[v].x = acc[v].x * invl; val[v].y = acc[v].y * invl;
    val[v].z = acc[v].z * invl; val[v].w = acc[v].w * invl;
  }
#pragma unroll
  for (int d = 0; d < 16; ++d) {
    float td = __shfl(tn, (lane & 48) | d);
    const float* wb = we + d * HD + h * DOUT + c0;
#pragma unroll
    for (int v = 0; v < NV; ++v) {
      float4 w4 = *reinterpret_cast<const float4*>(wb + 4 * v);
      val[v].x += td * w4.x; val[v].y += td * w4.y;
      val[v].z += td * w4.z; val[v].w += td * w4.w;
    }
  }
#pragma unroll
  for (int v = 0; v < NV; ++v) {
    val[v].x += __shfl_xor(val[v].x, 16); val[v].x += __shfl_xor(val[v].x, 32);
    val[v].y += __shfl_xor(val[v].y, 16); val[v].y += __shfl_xor(val[v].y, 32);
    val[v].z += __shfl_xor(val[v].z, 16); val[v].z += __shfl_xor(val[v].z, 32);
    val[v].w += __shfl_xor(val[v].w, 16); val[v].w += __shfl_xor(val[v].w, 32);
  }
  if (h == 0) {
    KWT sw = *reinterpret_cast<const KWT*>(base + HD + 64 + c0);
    float4 sk[NV];
    cvt_kv(sw, sk);
#pragma unroll
    for (int v = 0; v < NV; ++v) {
      float4 o;
      o.x = 0.25f * val[v].x + sk[v].x;
      o.y = 0.25f * val[v].y + sk[v].y;
      o.z = 0.25f * val[v].z + sk[v].z;
      o.w = 0.25f * val[v].w + sk[v].w;
      o.x = (o.x > 0.f) ? o.x : expm1f(o.x);
      o.y = (o.y > 0.f) ? o.y : expm1f(o.y);
      o.z = (o.z > 0.f) ? o.z : expm1f(o.z);
      o.w = (o.w > 0.f) ? o.w : expm1f(o.w);
      *reinterpret_cast<float4*>(out + (size_t)n * DOUT + c0 + 4 * v) = o;
      __half2* o16 = reinterpret_cast<__half2*>(out16 + (size_t)n * DOUT + c0 + 4 * v);
      o16[0] = __floats2half2_rn(o.x, o.y);
      o16[1] = __floats2half2_rn(o.z, o.w);
    }
  }
}

// ---------------------------------------------------------------------------
// Global mean pool (batch sorted -> contiguous per-graph ranges)
// ---------------------------------------------------------------------------
__device__ inline int lower_bound(const int* b, int n, int v) {
  int lo = 0, hi = n;
  while (lo < hi) {
    int mid = (lo + hi) >> 1;
    if (b[mid] < v) lo = mid + 1; else hi = mid;
  }
  return lo;
}

__global__ __launch_bounds__(256) void pool_all(const float* __restrict__ h,
                                                const int* __restrict__ batch,
                                                float* __restrict__ out) {
  const int g = blockIdx.x;
  const int start = lower_bound(batch, N_NODES, g);
  const int end = lower_bound(batch, N_NODES, g + 1);
  const int c = threadIdx.x & 63, j = threadIdx.x >> 6;
  float s = 0.f;
  for (int n = start + j; n < end; n += 4) s += h[(size_t)n * 64 + c];
  __shared__ float red[4][64];
  red[j][c] = s;
  __syncthreads();
  if (j == 0) {
    float tot = red[0][c] + red[1][c] + red[2][c] + red[3][c];
    out[g * 64 + c] = tot / (float)max(end - start, 1);
  }
}

// ---------------------------------------------------------------------------
extern "C" void kernel_launch(void* const* d_in, const int* in_sizes, int n_in,
                              void* d_out, int out_size, void* d_ws, size_t ws_size,
                              hipStream_t stream) {
  const float* x = (const float*)d_in[0];
  const int* edge_index = (const int*)d_in[1];
  const float* edge_attr = (const float*)d_in[2];
  const int* batch = (const int*)d_in[3];
  const int* srcp = edge_index;
  const int* dstp = edge_index + N_EDGES;

  const bool dict_order = in_sizes[5] > 1024;
  const float *wq[3], *wk[3], *wv[3], *wep[3], *wsk[3], *bq[3], *bk[3], *bv[3], *bs[3];
  for (int L = 0; L < 3; ++L) {
    int b = 4 + L * 9;
    if (dict_order) {
      wq[L] = (const float*)d_in[b + 0];
      wk[L] = (const float*)d_in[b + 1];
      wv[L] = (const float*)d_in[b + 2];
      wep[L] = (const float*)d_in[b + 3];
      wsk[L] = (const float*)d_in[b + 4];
      bq[L] = (const float*)d_in[b + 5];
      bk[L] = (const float*)d_in[b + 6];
      bv[L] = (const float*)d_in[b + 7];
      bs[L] = (const float*)d_in[b + 8];
    } else {
      wq[L] = (const float*)d_in[b + 0];
      bq[L] = (const float*)d_in[b + 1];
      wk[L] = (const float*)d_in[b + 2];
      bk[L] = (const float*)d_in[b + 3];
      wv[L] = (const float*)d_in[b + 4];
      bv[L] = (const float*)d_in[b + 5];
      wep[L] = (const float*)d_in[b + 6];
      wsk[L] = (const float*)d_in[b + 7];
      bs[L] = (const float*)d_in[b + 8];
    }
  }

  // Workspace carve (bytes).
  char* p = (char*)d_ws;
  __half* qs = (__half*)p;    p += (size_t)N_NODES * 704 * 2;   // Q|G|S f16 (max L2)
  __half* kv = (__half*)p;    p += (size_t)N_NODES * 1024 * 2;  // K|V f16 (max L2)
  float* h1 = (float*)p;      p += (size_t)N_NODES * 64 * 4;
  float* h2 = (float*)p;      p += (size_t)N_NODES * 128 * 4;
  __half* x16 = (__half*)p;   p += (size_t)N_NODES * 128 * 2;
  __half* h16 = (__half*)p;   p += (size_t)N_NODES * 128 * 2;
  __half* W1 = (__half*)p;    p += 128 * 896 * 2;
  __half* W2 = (__half*)p;    p += 64 * 1728 * 2;
  __half* W3 = (__half*)p;    p += 128 * 896 * 2;
  float* b1 = (float*)p;      p += 896 * 4;
  float* b2 = (float*)p;      p += 1728 * 4;
  float* b3 = (float*)p;      p += 896 * 4;
  float* csr_ea = (float*)p;  p += (size_t)N_EDGES * 16 * 4;
  int* cnt = (int*)p;         p += N_NODES * 4;
  int* cursor = (int*)p;      p += N_NODES * 4;
  int* offs = (int*)p;        p += (N_NODES + 1) * 4;
  int* csr_src = (int*)p;     p += N_EDGES * 4;

  // ---- pack weights (f16 frag order, fused G cols) + x->f16 (1 launch) ----
  pack_all<<<1024, 256, 0, stream>>>(
      wq[0], wk[0], wv[0], wsk[0], wep[0], bq[0], bk[0], bv[0], bs[0],
      wq[1], wk[1], wv[1], wsk[1], wep[1], bq[1], bk[1], bv[1], bs[1],
      wq[2], wk[2], wv[2], wsk[2], wep[2], bq[2], bk[2], bv[2], bs[2],
      W1, b1, W2, b2, W3, b3, x, x16);

  // ---- CSR build over dst ----
  hipMemsetAsync(cnt, 0, 2 * N_NODES * sizeof(int), stream);  // cnt + cursor
  count_dst<<<(N_EDGES + 255) / 256, 256, 0, stream>>>(dstp, cnt);
  scan_offs<<<1, 256, 0, stream>>>(cnt, offs);
  scatter_csr<<<(N_EDGES + 255) / 256, 256, 0, stream>>>(srcp, dstp, edge_attr,
                                                         offs, cursor, csr_src, csr_ea);

  const int MT = (N_NODES + 63) / 64;
  // ---- layer 1: K=128, HD=256, DOUT=64 ----
  gemm_mfma<128, 256, 64><<<dim3(896 / 64, MT), 256, 0, stream>>>(x16, W1, b1, qs,
                                                                  kv, N_NODES);
  edge_attn<64><<<N_NODES / 4, 256, 0, stream>>>(qs, kv, wep[0], csr_src, csr_ea,
                                                 offs, h1, h16);
  // ---- layer 2: K=64, HD=512, DOUT=128 ----
  gemm_mfma<64, 512, 128><<<dim3(1728 / 64, MT), 256, 0, stream>>>(h16, W2, b2, qs,
                                                                   kv, N_NODES);
  edge_attn<128><<<N_NODES / 4, 256, 0, stream>>>(qs, kv, wep[1], csr_src, csr_ea,
                                                  offs, h2, h16);
  // ---- layer 3: K=128, HD=256, DOUT=64 ----
  gemm_mfma<128, 256, 64><<<dim3(896 / 64, MT), 256, 0, stream>>>(h16, W3, b3, qs,
                                                                  kv, N_NODES);
  edge_attn<64><<<N_NODES / 4, 256, 0, stream>>>(qs, kv, wep[2], csr_src, csr_ea,
                                                 offs, h1, x16 /*scratch*/);

  // ---- global mean pool ----
  pool_all<<<N_GRAPHS, 256, 0, stream>>>(h1, batch, (float*)d_out);
}